// Round 3
// baseline (998.435 us; speedup 1.0000x reference)
//
#include <hip/hip_runtime.h>
#include <hip/hip_bf16.h>

// WeightedHGTConv: N=50000 nodes, E=400000 edges, D=128, T=4 types, R=8 rels,
// H=8 heads, DK=16.
// Pipeline: memset -> hist -> scan -> scatter(sort+pack) -> proj(QKV) -> fused agg
// (scores computed on the fly, flash-style online softmax; no E*H scores array).

#define D 128
#define NT 4
#define NR 8
#define NH 8

// ---------------------------------------------------------------- histogram
__global__ void k_hist(const int* __restrict__ nt, const int* __restrict__ ei,
                       int N, int E, int* __restrict__ tcnt, int* __restrict__ deg) {
    int g = blockIdx.x * 256 + threadIdx.x;
    if (g < N) atomicAdd(&tcnt[nt[g]], 1);
    if (g < E) atomicAdd(&deg[ei[E + g]], 1);
}

// ---------------------------------------------------------------- scan (1 block)
__global__ __launch_bounds__(1024) void k_scan(const int* __restrict__ deg,
                                               const int* __restrict__ tcnt, int N,
                                               int* __restrict__ row_ptr,
                                               int* __restrict__ ecur,
                                               int* __restrict__ toff) {
    __shared__ int lds[1024];
    int ti = threadIdx.x;
    int chunk = (N + 1023) / 1024;
    int s = ti * chunk;
    int e = min(N, s + chunk);
    int sum = 0;
    for (int i = s; i < e; i++) sum += deg[i];
    lds[ti] = sum;
    __syncthreads();
    for (int off = 1; off < 1024; off <<= 1) {
        int v = (ti >= off) ? lds[ti - off] : 0;
        __syncthreads();
        lds[ti] += v;
        __syncthreads();
    }
    int run = lds[ti] - sum;  // exclusive prefix
    for (int i = s; i < e; i++) {
        row_ptr[i] = run;
        ecur[i] = run;
        run += deg[i];
    }
    if (ti == 1023) row_ptr[N] = run;
    if (ti == 0) {
        int a = 0;
        for (int t = 0; t < NT; t++) { toff[t] = a; a += tcnt[t]; }
        toff[NT] = a;
    }
}

// ------------------------------------------- scatter (counting sorts + edge pack)
// CSR slot gets one packed record: src | (rel<<17) | ((sign+1)<<20).
// src < 50000 < 2^17, rel < 8 (3 bits), sign+1 in {0,1,2} (2 bits).
__global__ void k_scatter(const int* __restrict__ nt, const int* __restrict__ ei,
                          const int* __restrict__ et, const int* __restrict__ es,
                          int N, int E, int* __restrict__ tcur,
                          const int* __restrict__ toff, int* __restrict__ sorted,
                          int* __restrict__ ecur, int* __restrict__ csr_rec) {
    int g = blockIdx.x * 256 + threadIdx.x;
    if (g < N) {
        int t = nt[g];
        int p = atomicAdd(&tcur[t], 1);
        sorted[toff[t] + p] = g;
    }
    if (g < E) {
        int src = ei[g];
        int d = ei[E + g];
        int r = et[g];
        int sg = es[g];
        int p = atomicAdd(&ecur[d], 1);
        csr_rec[p] = src | (r << 17) | ((sg + 1) << 20);
    }
}

// ---------------------------------------------------------------- projections
// Block = 256 thr, 128 (type-uniform, sorted) nodes. x tile in LDS (stride 129
// floats: simultaneous rows differ by 8 -> banks +8 apart -> conflict-free).
// Thread = 8 nodes x 8 outs register tile; W streamed from L1/L2 (64KB/type).
__global__ __launch_bounds__(256, 2) void k_proj(
    const float* __restrict__ x, const int* __restrict__ sorted,
    const int* __restrict__ toff,
    const float* __restrict__ Wq, const float* __restrict__ bq,
    const float* __restrict__ Wk, const float* __restrict__ bk,
    const float* __restrict__ Wv, const float* __restrict__ bv,
    float* __restrict__ Q, float* __restrict__ K, float* __restrict__ V) {
    __shared__ float xs[128 * 129];
    __shared__ int sid[128];
    int tid = threadIdx.x;
    int b = blockIdx.x;
    // map block -> (type, slice of sorted[]) ; uniform across block
    int t = -1, p0 = 0;
    int cum = 0;
    for (int tt = 0; tt < NT; tt++) {
        int cnt_t = toff[tt + 1] - toff[tt];
        int nb = (cnt_t + 127) >> 7;
        if (t < 0 && b < cum + nb) { t = tt; p0 = toff[tt] + (b - cum) * 128; }
        cum += nb;
    }
    if (t < 0) return;
    int cnt = min(128, toff[t + 1] - p0);

    if (tid < 128) sid[tid] = (tid < cnt) ? sorted[p0 + tid] : -1;
    __syncthreads();
    // stage x rows (gathered) into LDS
    for (int j = 0; j < 16; j++) {
        int idx = j * 256 + tid;          // 4096 float4 slots
        int row = idx >> 5, c4 = (idx & 31) * 4;
        int node = sid[row];
        if (node >= 0) {
            float4 v = *(const float4*)(x + (size_t)node * D + c4);
            float* p = &xs[row * 129 + c4];
            p[0] = v.x; p[1] = v.y; p[2] = v.z; p[3] = v.w;
        }
    }
    __syncthreads();

    int og = tid & 15, ng = tid >> 4;
    int o0 = og * 8;
    const float* Ws[3] = {Wq + (size_t)t * D * D, Wk + (size_t)t * D * D, Wv + (size_t)t * D * D};
    const float* bs[3] = {bq + t * D, bk + t * D, bv + t * D};
    float* Os[3] = {Q, K, V};

    for (int m = 0; m < 3; m++) {
        const float* Wm = Ws[m];
        const float* bm = bs[m];
        float acc[8][8];
        float bias[8];
#pragma unroll
        for (int c = 0; c < 8; c++) bias[c] = bm[o0 + c];
#pragma unroll
        for (int r = 0; r < 8; r++)
#pragma unroll
            for (int c = 0; c < 8; c++) acc[r][c] = bias[c];

#pragma unroll 2
        for (int k = 0; k < D; k++) {
            float4 w0 = *(const float4*)(Wm + k * D + o0);
            float4 w1 = *(const float4*)(Wm + k * D + o0 + 4);
            float w8[8] = {w0.x, w0.y, w0.z, w0.w, w1.x, w1.y, w1.z, w1.w};
            float xv[8];
#pragma unroll
            for (int r = 0; r < 8; r++) xv[r] = xs[(ng * 8 + r) * 129 + k];
#pragma unroll
            for (int r = 0; r < 8; r++)
#pragma unroll
                for (int c = 0; c < 8; c++) acc[r][c] += xv[r] * w8[c];
        }
        float* Om = Os[m];
#pragma unroll
        for (int r = 0; r < 8; r++) {
            int node = sid[ng * 8 + r];
            if (node < 0) continue;
            float4 a0 = {acc[r][0], acc[r][1], acc[r][2], acc[r][3]};
            float4 a1 = {acc[r][4], acc[r][5], acc[r][6], acc[r][7]};
            *(float4*)(Om + (size_t)node * D + o0) = a0;
            *(float4*)(Om + (size_t)node * D + o0 + 4) = a1;
        }
    }
}

// ------------------------------- fused scores + softmax + aggregate + skip + LN
// One wave per dst node, flash-style online softmax over 8-edge chunks.
// Score pass layout: lane = h*8+li computes score(edge c0+li, head h) with a
//   full 16-dim dot in registers (K read as the lane's contiguous 64B segment).
// Accumulate pass layout: lane owns output dims {2*lane, 2*lane+1}, head=lane>>3.
// Scores/records cross layouts via __shfl — no LDS, no global scores array.
__global__ __launch_bounds__(256) void k_agg(
    const int* __restrict__ row_ptr, const int* __restrict__ csr_rec,
    const int* __restrict__ nt, const float* __restrict__ x,
    const float* __restrict__ Qt, const float* __restrict__ Kt,
    const float* __restrict__ Vt, const float* __restrict__ rq,
    const float* __restrict__ rk, const float* __restrict__ rv,
    const float* __restrict__ skn, const float* __restrict__ svn,
    const float* __restrict__ rb, const float* __restrict__ skip,
    const float* __restrict__ gamma, const float* __restrict__ beta,
    float* __restrict__ out, int N) {
    // rel tables in LDS, row stride 132 (banks offset by 4*r => <=2-way, free)
    __shared__ float l_rq[NR * 132];
    __shared__ float l_rk[NR * 132];
    __shared__ float l_rv[NR * 132];
    __shared__ float l_rb[NR * NH];
    int tid = threadIdx.x;
    for (int idx = tid; idx < NR * D; idx += 256) {
        int r = idx >> 7, c = idx & 127;
        l_rq[r * 132 + c] = rq[idx];
        l_rk[r * 132 + c] = rk[idx];
        l_rv[r * 132 + c] = rv[idx];
    }
    if (tid < NR * NH) l_rb[tid] = rb[tid];
    __syncthreads();

    int wid = (blockIdx.x * 256 + tid) >> 6;
    if (wid >= N) return;
    int lane = tid & 63;
    int h = lane >> 3, li = lane & 7;
    int d0 = lane * 2;
    int dst = wid;
    int rp0 = row_ptr[dst];
    int deg = row_ptr[dst + 1] - rp0;

    // loop-invariant preloads
    float4 q4[4], sk4[4];
#pragma unroll
    for (int j = 0; j < 4; j++) {
        q4[j] = *(const float4*)(Qt + (size_t)dst * D + h * 16 + 4 * j);
        sk4[j] = *(const float4*)(skn + h * 16 + 4 * j);
    }
    float2 sv2 = *(const float2*)(svn + d0);
    float2 xi = *(const float2*)(x + (size_t)dst * D + d0);
    int t = nt[dst];

    float m = -INFINITY, lsum = 0.f, acc0 = 0.f, acc1 = 0.f;

    for (int c0 = 0; c0 < deg; c0 += 8) {
        int cn = min(8, deg - c0);
        // ---- score pass: lane (h, li) -> score(edge c0+li, head h)
        bool valid = li < cn;
        int recA = csr_rec[rp0 + c0 + (valid ? li : 0)];
        int srcA = recA & 0x1FFFF;
        int rA = (recA >> 17) & 7;
        int sgA = ((recA >> 20) & 3) - 1;
        bool neuA = (sgA == 0);
        float fsgA = (float)sgA;
        const float* kp = Kt + (size_t)srcA * D + h * 16;
        const float* rqp = &l_rq[rA * 132 + h * 16];
        const float* rkp = &l_rk[rA * 132 + h * 16];
        float dot = 0.f;
#pragma unroll
        for (int j = 0; j < 4; j++) {
            float4 k4 = *(const float4*)(kp + 4 * j);
            float4 a4 = *(const float4*)(rqp + 4 * j);
            float4 b4 = *(const float4*)(rkp + 4 * j);
            float f0 = neuA ? sk4[j].x : fsgA;
            float f1 = neuA ? sk4[j].y : fsgA;
            float f2 = neuA ? sk4[j].z : fsgA;
            float f3 = neuA ? sk4[j].w : fsgA;
            dot += q4[j].x * a4.x * k4.x * b4.x * f0;
            dot += q4[j].y * a4.y * k4.y * b4.y * f1;
            dot += q4[j].z * a4.z * k4.z * b4.z * f2;
            dot += q4[j].w * a4.w * k4.w * b4.w * f3;
        }
        float scA = valid ? dot * 0.25f + l_rb[rA * NH + h] : -INFINITY;
        // chunk max per head (reduce over li within the head group)
        float cm = scA;
        cm = fmaxf(cm, __shfl_xor(cm, 1));
        cm = fmaxf(cm, __shfl_xor(cm, 2));
        cm = fmaxf(cm, __shfl_xor(cm, 4));
        float nm = fmaxf(m, cm);
        float resc = __expf(m - nm);   // 0 on first chunk (m = -inf)
        acc0 *= resc; acc1 *= resc; lsum *= resc;
        m = nm;
        // ---- accumulate pass: lane owns dims d0, d0+1 of head h
        for (int i = 0; i < cn; ++i) {
            int rec = __shfl(recA, i);                     // edge i's record
            float s = __shfl(scA, (lane & 56) | i);        // score(i, my head)
            int src = rec & 0x1FFFF;
            int r = (rec >> 17) & 7;
            int sg = ((rec >> 20) & 3) - 1;
            float w = __expf(s - m);
            lsum += w;
            float2 v2 = *(const float2*)(Vt + (size_t)src * D + d0);
            float2 r2 = *(const float2*)(&l_rv[r * 132 + d0]);
            bool neu = (sg == 0);
            float f0 = neu ? sv2.x : (float)sg;
            float f1 = neu ? sv2.y : (float)sg;
            acc0 += w * v2.x * r2.x * f0;
            acc1 += w * v2.y * r2.y * f1;
        }
    }
    float winv = 1.f / (lsum + 1e-16f);
    float a0 = acc0 * winv, a1 = acc1 * winv;

    // gated skip + layernorm epilogue
    float alpha = 1.f / (1.f + __expf(-skip[t]));
    float p0 = alpha * a0 + (1.f - alpha) * xi.x;
    float p1 = alpha * a1 + (1.f - alpha) * xi.y;
    float rs = p0 + p1, rsq = p0 * p0 + p1 * p1;
#pragma unroll
    for (int o = 1; o < 64; o <<= 1) {
        rs += __shfl_xor(rs, o);
        rsq += __shfl_xor(rsq, o);
    }
    float mu = rs * (1.f / 128.f);
    float var = rsq * (1.f / 128.f) - mu * mu;
    float rstd = rsqrtf(var + 1e-5f);
    float2 g2 = *(const float2*)(gamma + t * D + d0);
    float2 b2 = *(const float2*)(beta + t * D + d0);
    float o0 = (p0 - mu) * rstd * g2.x + b2.x;
    float o1 = (p1 - mu) * rstd * g2.y + b2.y;
    *(float2*)(out + (size_t)dst * D + d0) = make_float2(o0, o1);
}

// ---------------------------------------------------------------- launcher
extern "C" void kernel_launch(void* const* d_in, const int* in_sizes, int n_in,
                              void* d_out, int out_size, void* d_ws, size_t ws_size,
                              hipStream_t stream) {
    const float* x   = (const float*)d_in[0];
    const int*  nt   = (const int*)d_in[1];
    const int*  ei   = (const int*)d_in[2];
    const int*  et   = (const int*)d_in[3];
    const int*  es   = (const int*)d_in[4];
    const float* Wq  = (const float*)d_in[5];
    const float* bq  = (const float*)d_in[6];
    const float* Wk  = (const float*)d_in[7];
    const float* bk  = (const float*)d_in[8];
    const float* Wv  = (const float*)d_in[9];
    const float* bv  = (const float*)d_in[10];
    const float* rq  = (const float*)d_in[11];
    const float* rk  = (const float*)d_in[12];
    const float* rv  = (const float*)d_in[13];
    const float* skn = (const float*)d_in[14];
    const float* svn = (const float*)d_in[15];
    const float* rb  = (const float*)d_in[16];
    const float* skp = (const float*)d_in[17];
    const float* gma = (const float*)d_in[18];
    const float* bta = (const float*)d_in[19];
    float* out = (float*)d_out;

    int N = in_sizes[0] / D;   // 50000
    int E = in_sizes[2] / 2;   // 400000

    // workspace layout
    float* Q = (float*)d_ws;
    float* K = Q + (size_t)N * D;
    float* V = K + (size_t)N * D;
    int* deg     = (int*)(V + (size_t)N * D);
    int* tcnt    = deg + N;                       // 4
    int* tcur    = tcnt + NT;                     // 4
    int* row_ptr = tcur + NT;                     // N+1
    int* ecur    = row_ptr + N + 1;               // N
    int* toff    = ecur + N;                      // 5 (pad 8)
    int* sorted  = toff + 8;                      // N
    int* csr_rec = sorted + N;                    // E (packed records)

    // zero the atomic counters/histograms (deg | tcnt | tcur contiguous)
    hipMemsetAsync(deg, 0, (size_t)(N + 2 * NT) * sizeof(int), stream);

    int gbNE = (max(N, E) + 255) / 256;
    k_hist<<<gbNE, 256, 0, stream>>>(nt, ei, N, E, tcnt, deg);
    k_scan<<<1, 1024, 0, stream>>>(deg, tcnt, N, row_ptr, ecur, toff);
    k_scatter<<<gbNE, 256, 0, stream>>>(nt, ei, et, es, N, E, tcur, toff, sorted,
                                        ecur, csr_rec);
    k_proj<<<(N + 127) / 128 + NT, 256, 0, stream>>>(x, sorted, toff, Wq, bq, Wk, bk,
                                                     Wv, bv, Q, K, V);
    k_agg<<<(N * 64 + 255) / 256, 256, 0, stream>>>(row_ptr, csr_rec, nt, x, Q, K, V,
                                                    rq, rk, rv, skn, svn, rb, skp,
                                                    gma, bta, out, N);
}

// Round 4
// 479.854 us; speedup vs baseline: 2.0807x; 2.0807x over previous
//
#include <hip/hip_runtime.h>
#include <hip/hip_bf16.h>

// WeightedHGTConv: N=50000 nodes, E=400000 edges, D=128, T=4 types, R=8 rels,
// H=8 heads, DK=16.
// Pipeline: memset -> hist -> scan -> scatter(sort+pack) -> proj(QKV) -> fused agg
// (scores computed on the fly, flash-style online softmax; no E*H scores array).
// R3 fix: 4-address value-returning global atomics (12.5k-way contention, 280us)
// replaced by block-level LDS aggregation in k_hist/k_scatter.

#define D 128
#define NT 4
#define NR 8
#define NH 8

// ---------------------------------------------------------------- histogram
__global__ void k_hist(const int* __restrict__ nt, const int* __restrict__ ei,
                       int N, int E, int* __restrict__ tcnt, int* __restrict__ deg) {
    __shared__ int lcnt[NT];
    int tid = threadIdx.x;
    if (tid < NT) lcnt[tid] = 0;
    __syncthreads();
    int g = blockIdx.x * 256 + tid;
    if (g < N) atomicAdd(&lcnt[nt[g]], 1);              // LDS, cheap
    if (g < E) atomicAdd(&deg[ei[E + g]], 1);           // 50k counters, fire&forget
    __syncthreads();
    if (tid < NT && lcnt[tid]) atomicAdd(&tcnt[tid], lcnt[tid]);  // 4/block
}

// ---------------------------------------------------------------- scan (1 block)
__global__ __launch_bounds__(1024) void k_scan(const int* __restrict__ deg,
                                               const int* __restrict__ tcnt, int N,
                                               int* __restrict__ row_ptr,
                                               int* __restrict__ ecur,
                                               int* __restrict__ toff) {
    __shared__ int lds[1024];
    int ti = threadIdx.x;
    int chunk = (N + 1023) / 1024;
    int s = ti * chunk;
    int e = min(N, s + chunk);
    int sum = 0;
    for (int i = s; i < e; i++) sum += deg[i];
    lds[ti] = sum;
    __syncthreads();
    for (int off = 1; off < 1024; off <<= 1) {
        int v = (ti >= off) ? lds[ti - off] : 0;
        __syncthreads();
        lds[ti] += v;
        __syncthreads();
    }
    int run = lds[ti] - sum;  // exclusive prefix
    for (int i = s; i < e; i++) {
        row_ptr[i] = run;
        ecur[i] = run;
        run += deg[i];
    }
    if (ti == 1023) row_ptr[N] = run;
    if (ti == 0) {
        int a = 0;
        for (int t = 0; t < NT; t++) { toff[t] = a; a += tcnt[t]; }
        toff[NT] = a;
    }
}

// ------------------------------------------- scatter (counting sorts + edge pack)
// Node half: LDS rank within block + one global atomic per (block,type).
// Edge half: CSR slot gets packed record: src | (rel<<17) | ((sign+1)<<20).
__global__ void k_scatter(const int* __restrict__ nt, const int* __restrict__ ei,
                          const int* __restrict__ et, const int* __restrict__ es,
                          int N, int E, int* __restrict__ tcur,
                          const int* __restrict__ toff, int* __restrict__ sorted,
                          int* __restrict__ ecur, int* __restrict__ csr_rec) {
    __shared__ int lcnt[NT];
    __shared__ int lbase[NT];
    int tid = threadIdx.x;
    if (tid < NT) lcnt[tid] = 0;
    __syncthreads();
    int g = blockIdx.x * 256 + tid;
    int t = -1, myrank = 0;
    if (g < N) {
        t = nt[g];
        myrank = atomicAdd(&lcnt[t], 1);                // LDS-speed rank
    }
    __syncthreads();
    if (tid < NT) lbase[tid] = lcnt[tid] ? atomicAdd(&tcur[tid], lcnt[tid]) : 0;
    __syncthreads();
    if (t >= 0) sorted[toff[t] + lbase[t] + myrank] = g;

    if (g < E) {
        int src = ei[g];
        int d = ei[E + g];
        int r = et[g];
        int sg = es[g];
        int p = atomicAdd(&ecur[d], 1);                 // 50k counters, ~8-way
        csr_rec[p] = src | (r << 17) | ((sg + 1) << 20);
    }
}

// ---------------------------------------------------------------- projections
// Block = 256 thr, 128 (type-uniform, sorted) nodes. x tile in LDS (stride 129
// floats: simultaneous rows differ by 8 -> banks +8 apart -> conflict-free).
// Thread = 8 nodes x 8 outs register tile; W streamed from L1/L2 (64KB/type).
__global__ __launch_bounds__(256, 2) void k_proj(
    const float* __restrict__ x, const int* __restrict__ sorted,
    const int* __restrict__ toff,
    const float* __restrict__ Wq, const float* __restrict__ bq,
    const float* __restrict__ Wk, const float* __restrict__ bk,
    const float* __restrict__ Wv, const float* __restrict__ bv,
    float* __restrict__ Q, float* __restrict__ K, float* __restrict__ V) {
    __shared__ float xs[128 * 129];
    __shared__ int sid[128];
    int tid = threadIdx.x;
    int b = blockIdx.x;
    // map block -> (type, slice of sorted[]) ; uniform across block
    int t = -1, p0 = 0;
    int cum = 0;
    for (int tt = 0; tt < NT; tt++) {
        int cnt_t = toff[tt + 1] - toff[tt];
        int nb = (cnt_t + 127) >> 7;
        if (t < 0 && b < cum + nb) { t = tt; p0 = toff[tt] + (b - cum) * 128; }
        cum += nb;
    }
    if (t < 0) return;
    int cnt = min(128, toff[t + 1] - p0);

    if (tid < 128) sid[tid] = (tid < cnt) ? sorted[p0 + tid] : -1;
    __syncthreads();
    // stage x rows (gathered) into LDS
    for (int j = 0; j < 16; j++) {
        int idx = j * 256 + tid;          // 4096 float4 slots
        int row = idx >> 5, c4 = (idx & 31) * 4;
        int node = sid[row];
        if (node >= 0) {
            float4 v = *(const float4*)(x + (size_t)node * D + c4);
            float* p = &xs[row * 129 + c4];
            p[0] = v.x; p[1] = v.y; p[2] = v.z; p[3] = v.w;
        }
    }
    __syncthreads();

    int og = tid & 15, ng = tid >> 4;
    int o0 = og * 8;
    const float* Ws[3] = {Wq + (size_t)t * D * D, Wk + (size_t)t * D * D, Wv + (size_t)t * D * D};
    const float* bs[3] = {bq + t * D, bk + t * D, bv + t * D};
    float* Os[3] = {Q, K, V};

    for (int m = 0; m < 3; m++) {
        const float* Wm = Ws[m];
        const float* bm = bs[m];
        float acc[8][8];
        float bias[8];
#pragma unroll
        for (int c = 0; c < 8; c++) bias[c] = bm[o0 + c];
#pragma unroll
        for (int r = 0; r < 8; r++)
#pragma unroll
            for (int c = 0; c < 8; c++) acc[r][c] = bias[c];

#pragma unroll 2
        for (int k = 0; k < D; k++) {
            float4 w0 = *(const float4*)(Wm + k * D + o0);
            float4 w1 = *(const float4*)(Wm + k * D + o0 + 4);
            float w8[8] = {w0.x, w0.y, w0.z, w0.w, w1.x, w1.y, w1.z, w1.w};
            float xv[8];
#pragma unroll
            for (int r = 0; r < 8; r++) xv[r] = xs[(ng * 8 + r) * 129 + k];
#pragma unroll
            for (int r = 0; r < 8; r++)
#pragma unroll
                for (int c = 0; c < 8; c++) acc[r][c] += xv[r] * w8[c];
        }
        float* Om = Os[m];
#pragma unroll
        for (int r = 0; r < 8; r++) {
            int node = sid[ng * 8 + r];
            if (node < 0) continue;
            float4 a0 = {acc[r][0], acc[r][1], acc[r][2], acc[r][3]};
            float4 a1 = {acc[r][4], acc[r][5], acc[r][6], acc[r][7]};
            *(float4*)(Om + (size_t)node * D + o0) = a0;
            *(float4*)(Om + (size_t)node * D + o0 + 4) = a1;
        }
    }
}

// ------------------------------- fused scores + softmax + aggregate + skip + LN
// One wave per dst node, flash-style online softmax over 8-edge chunks.
// Score pass layout: lane = h*8+li computes score(edge c0+li, head h) with a
//   full 16-dim dot in registers (K read as the lane's contiguous 64B segment).
// Accumulate pass layout: lane owns output dims {2*lane, 2*lane+1}, head=lane>>3.
// Scores/records cross layouts via __shfl — no LDS, no global scores array.
__global__ __launch_bounds__(256) void k_agg(
    const int* __restrict__ row_ptr, const int* __restrict__ csr_rec,
    const int* __restrict__ nt, const float* __restrict__ x,
    const float* __restrict__ Qt, const float* __restrict__ Kt,
    const float* __restrict__ Vt, const float* __restrict__ rq,
    const float* __restrict__ rk, const float* __restrict__ rv,
    const float* __restrict__ skn, const float* __restrict__ svn,
    const float* __restrict__ rb, const float* __restrict__ skip,
    const float* __restrict__ gamma, const float* __restrict__ beta,
    float* __restrict__ out, int N) {
    // rel tables in LDS, row stride 132 (banks offset by 4*r => <=2-way, free)
    __shared__ float l_rq[NR * 132];
    __shared__ float l_rk[NR * 132];
    __shared__ float l_rv[NR * 132];
    __shared__ float l_rb[NR * NH];
    int tid = threadIdx.x;
    for (int idx = tid; idx < NR * D; idx += 256) {
        int r = idx >> 7, c = idx & 127;
        l_rq[r * 132 + c] = rq[idx];
        l_rk[r * 132 + c] = rk[idx];
        l_rv[r * 132 + c] = rv[idx];
    }
    if (tid < NR * NH) l_rb[tid] = rb[tid];
    __syncthreads();

    int wid = (blockIdx.x * 256 + tid) >> 6;
    if (wid >= N) return;
    int lane = tid & 63;
    int h = lane >> 3, li = lane & 7;
    int d0 = lane * 2;
    int dst = wid;
    int rp0 = row_ptr[dst];
    int deg = row_ptr[dst + 1] - rp0;

    // loop-invariant preloads
    float4 q4[4], sk4[4];
#pragma unroll
    for (int j = 0; j < 4; j++) {
        q4[j] = *(const float4*)(Qt + (size_t)dst * D + h * 16 + 4 * j);
        sk4[j] = *(const float4*)(skn + h * 16 + 4 * j);
    }
    float2 sv2 = *(const float2*)(svn + d0);
    float2 xi = *(const float2*)(x + (size_t)dst * D + d0);
    int t = nt[dst];

    float m = -INFINITY, lsum = 0.f, acc0 = 0.f, acc1 = 0.f;

    for (int c0 = 0; c0 < deg; c0 += 8) {
        int cn = min(8, deg - c0);
        // ---- score pass: lane (h, li) -> score(edge c0+li, head h)
        bool valid = li < cn;
        int recA = csr_rec[rp0 + c0 + (valid ? li : 0)];
        int srcA = recA & 0x1FFFF;
        int rA = (recA >> 17) & 7;
        int sgA = ((recA >> 20) & 3) - 1;
        bool neuA = (sgA == 0);
        float fsgA = (float)sgA;
        const float* kp = Kt + (size_t)srcA * D + h * 16;
        const float* rqp = &l_rq[rA * 132 + h * 16];
        const float* rkp = &l_rk[rA * 132 + h * 16];
        float dot = 0.f;
#pragma unroll
        for (int j = 0; j < 4; j++) {
            float4 k4 = *(const float4*)(kp + 4 * j);
            float4 a4 = *(const float4*)(rqp + 4 * j);
            float4 b4 = *(const float4*)(rkp + 4 * j);
            float f0 = neuA ? sk4[j].x : fsgA;
            float f1 = neuA ? sk4[j].y : fsgA;
            float f2 = neuA ? sk4[j].z : fsgA;
            float f3 = neuA ? sk4[j].w : fsgA;
            dot += q4[j].x * a4.x * k4.x * b4.x * f0;
            dot += q4[j].y * a4.y * k4.y * b4.y * f1;
            dot += q4[j].z * a4.z * k4.z * b4.z * f2;
            dot += q4[j].w * a4.w * k4.w * b4.w * f3;
        }
        float scA = valid ? dot * 0.25f + l_rb[rA * NH + h] : -INFINITY;
        // chunk max per head (reduce over li within the head group)
        float cm = scA;
        cm = fmaxf(cm, __shfl_xor(cm, 1));
        cm = fmaxf(cm, __shfl_xor(cm, 2));
        cm = fmaxf(cm, __shfl_xor(cm, 4));
        float nm = fmaxf(m, cm);
        float resc = __expf(m - nm);   // 0 on first chunk (m = -inf)
        acc0 *= resc; acc1 *= resc; lsum *= resc;
        m = nm;
        // ---- accumulate pass: lane owns dims d0, d0+1 of head h
        for (int i = 0; i < cn; ++i) {
            int rec = __shfl(recA, i);                     // edge i's record
            float s = __shfl(scA, (lane & 56) | i);        // score(i, my head)
            int src = rec & 0x1FFFF;
            int r = (rec >> 17) & 7;
            int sg = ((rec >> 20) & 3) - 1;
            float w = __expf(s - m);
            lsum += w;
            float2 v2 = *(const float2*)(Vt + (size_t)src * D + d0);
            float2 r2 = *(const float2*)(&l_rv[r * 132 + d0]);
            bool neu = (sg == 0);
            float f0 = neu ? sv2.x : (float)sg;
            float f1 = neu ? sv2.y : (float)sg;
            acc0 += w * v2.x * r2.x * f0;
            acc1 += w * v2.y * r2.y * f1;
        }
    }
    float winv = 1.f / (lsum + 1e-16f);
    float a0 = acc0 * winv, a1 = acc1 * winv;

    // gated skip + layernorm epilogue
    float alpha = 1.f / (1.f + __expf(-skip[t]));
    float p0 = alpha * a0 + (1.f - alpha) * xi.x;
    float p1 = alpha * a1 + (1.f - alpha) * xi.y;
    float rs = p0 + p1, rsq = p0 * p0 + p1 * p1;
#pragma unroll
    for (int o = 1; o < 64; o <<= 1) {
        rs += __shfl_xor(rs, o);
        rsq += __shfl_xor(rsq, o);
    }
    float mu = rs * (1.f / 128.f);
    float var = rsq * (1.f / 128.f) - mu * mu;
    float rstd = rsqrtf(var + 1e-5f);
    float2 g2 = *(const float2*)(gamma + t * D + d0);
    float2 b2 = *(const float2*)(beta + t * D + d0);
    float o0 = (p0 - mu) * rstd * g2.x + b2.x;
    float o1 = (p1 - mu) * rstd * g2.y + b2.y;
    *(float2*)(out + (size_t)dst * D + d0) = make_float2(o0, o1);
}

// ---------------------------------------------------------------- launcher
extern "C" void kernel_launch(void* const* d_in, const int* in_sizes, int n_in,
                              void* d_out, int out_size, void* d_ws, size_t ws_size,
                              hipStream_t stream) {
    const float* x   = (const float*)d_in[0];
    const int*  nt   = (const int*)d_in[1];
    const int*  ei   = (const int*)d_in[2];
    const int*  et   = (const int*)d_in[3];
    const int*  es   = (const int*)d_in[4];
    const float* Wq  = (const float*)d_in[5];
    const float* bq  = (const float*)d_in[6];
    const float* Wk  = (const float*)d_in[7];
    const float* bk  = (const float*)d_in[8];
    const float* Wv  = (const float*)d_in[9];
    const float* bv  = (const float*)d_in[10];
    const float* rq  = (const float*)d_in[11];
    const float* rk  = (const float*)d_in[12];
    const float* rv  = (const float*)d_in[13];
    const float* skn = (const float*)d_in[14];
    const float* svn = (const float*)d_in[15];
    const float* rb  = (const float*)d_in[16];
    const float* skp = (const float*)d_in[17];
    const float* gma = (const float*)d_in[18];
    const float* bta = (const float*)d_in[19];
    float* out = (float*)d_out;

    int N = in_sizes[0] / D;   // 50000
    int E = in_sizes[2] / 2;   // 400000

    // workspace layout
    float* Q = (float*)d_ws;
    float* K = Q + (size_t)N * D;
    float* V = K + (size_t)N * D;
    int* deg     = (int*)(V + (size_t)N * D);
    int* tcnt    = deg + N;                       // 4
    int* tcur    = tcnt + NT;                     // 4
    int* row_ptr = tcur + NT;                     // N+1
    int* ecur    = row_ptr + N + 1;               // N
    int* toff    = ecur + N;                      // 5 (pad 8)
    int* sorted  = toff + 8;                      // N
    int* csr_rec = sorted + N;                    // E (packed records)

    // zero the atomic counters/histograms (deg | tcnt | tcur contiguous)
    hipMemsetAsync(deg, 0, (size_t)(N + 2 * NT) * sizeof(int), stream);

    int gbNE = (max(N, E) + 255) / 256;
    k_hist<<<gbNE, 256, 0, stream>>>(nt, ei, N, E, tcnt, deg);
    k_scan<<<1, 1024, 0, stream>>>(deg, tcnt, N, row_ptr, ecur, toff);
    k_scatter<<<gbNE, 256, 0, stream>>>(nt, ei, et, es, N, E, tcur, toff, sorted,
                                        ecur, csr_rec);
    k_proj<<<(N + 127) / 128 + NT, 256, 0, stream>>>(x, sorted, toff, Wq, bq, Wk, bk,
                                                     Wv, bv, Q, K, V);
    k_agg<<<(N * 64 + 255) / 256, 256, 0, stream>>>(row_ptr, csr_rec, nt, x, Q, K, V,
                                                    rq, rk, rv, skn, svn, rb, skp,
                                                    gma, bta, out, N);
}

// Round 6
// 462.875 us; speedup vs baseline: 2.1570x; 1.0367x over previous
//
#include <hip/hip_runtime.h>
#include <hip/hip_bf16.h>

// WeightedHGTConv: N=50000 nodes, E=400000 edges, D=128, T=4 types, R=8 rels,
// H=8 heads, DK=16.
// Pipeline: memset -> hist -> scan -> scatter(sort+pack) -> proj(QKV) -> fused agg
// R3: block-aggregated type counters (280us 4-address atomic contention fix).
// R4: k_proj 512thr/block (2x waves at same LDS: occupancy 8->16 waves/CU);
//     k_agg static-unrolled gather phase (8 independent V loads in flight).
// R5: resubmit of R4 (bench never ran — GPU acquisition timeout).

#define D 128
#define NT 4
#define NR 8
#define NH 8

// ---------------------------------------------------------------- histogram
__global__ void k_hist(const int* __restrict__ nt, const int* __restrict__ ei,
                       int N, int E, int* __restrict__ tcnt, int* __restrict__ deg) {
    __shared__ int lcnt[NT];
    int tid = threadIdx.x;
    if (tid < NT) lcnt[tid] = 0;
    __syncthreads();
    int g = blockIdx.x * 256 + tid;
    if (g < N) atomicAdd(&lcnt[nt[g]], 1);              // LDS, cheap
    if (g < E) atomicAdd(&deg[ei[E + g]], 1);           // 50k counters, fire&forget
    __syncthreads();
    if (tid < NT && lcnt[tid]) atomicAdd(&tcnt[tid], lcnt[tid]);  // 4/block
}

// ---------------------------------------------------------------- scan (1 block)
__global__ __launch_bounds__(1024) void k_scan(const int* __restrict__ deg,
                                               const int* __restrict__ tcnt, int N,
                                               int* __restrict__ row_ptr,
                                               int* __restrict__ ecur,
                                               int* __restrict__ toff) {
    __shared__ int lds[1024];
    int ti = threadIdx.x;
    int chunk = (N + 1023) / 1024;
    int s = ti * chunk;
    int e = min(N, s + chunk);
    int sum = 0;
    for (int i = s; i < e; i++) sum += deg[i];
    lds[ti] = sum;
    __syncthreads();
    for (int off = 1; off < 1024; off <<= 1) {
        int v = (ti >= off) ? lds[ti - off] : 0;
        __syncthreads();
        lds[ti] += v;
        __syncthreads();
    }
    int run = lds[ti] - sum;  // exclusive prefix
    for (int i = s; i < e; i++) {
        row_ptr[i] = run;
        ecur[i] = run;
        run += deg[i];
    }
    if (ti == 1023) row_ptr[N] = run;
    if (ti == 0) {
        int a = 0;
        for (int t = 0; t < NT; t++) { toff[t] = a; a += tcnt[t]; }
        toff[NT] = a;
    }
}

// ------------------------------------------- scatter (counting sorts + edge pack)
// Node half: LDS rank within block + one global atomic per (block,type).
// Edge half: CSR slot gets packed record: src | (rel<<17) | ((sign+1)<<20).
__global__ void k_scatter(const int* __restrict__ nt, const int* __restrict__ ei,
                          const int* __restrict__ et, const int* __restrict__ es,
                          int N, int E, int* __restrict__ tcur,
                          const int* __restrict__ toff, int* __restrict__ sorted,
                          int* __restrict__ ecur, int* __restrict__ csr_rec) {
    __shared__ int lcnt[NT];
    __shared__ int lbase[NT];
    int tid = threadIdx.x;
    if (tid < NT) lcnt[tid] = 0;
    __syncthreads();
    int g = blockIdx.x * 256 + tid;
    int t = -1, myrank = 0;
    if (g < N) {
        t = nt[g];
        myrank = atomicAdd(&lcnt[t], 1);                // LDS-speed rank
    }
    __syncthreads();
    if (tid < NT) lbase[tid] = lcnt[tid] ? atomicAdd(&tcur[tid], lcnt[tid]) : 0;
    __syncthreads();
    if (t >= 0) sorted[toff[t] + lbase[t] + myrank] = g;

    if (g < E) {
        int src = ei[g];
        int d = ei[E + g];
        int r = et[g];
        int sg = es[g];
        int p = atomicAdd(&ecur[d], 1);                 // 50k counters, ~8-way
        csr_rec[p] = src | (r << 17) | ((sg + 1) << 20);
    }
}

// ---------------------------------------------------------------- projections
// Block = 512 thr, 128 (type-uniform, sorted) nodes. x tile in LDS (stride 129).
// Thread = 4 nodes x 8 outs register tile. 2 blocks/CU (66.5KB LDS) = 16
// waves/CU — R4: doubled wave count at identical math order (bit-exact).
__global__ __launch_bounds__(512, 4) void k_proj(
    const float* __restrict__ x, const int* __restrict__ sorted,
    const int* __restrict__ toff,
    const float* __restrict__ Wq, const float* __restrict__ bq,
    const float* __restrict__ Wk, const float* __restrict__ bk,
    const float* __restrict__ Wv, const float* __restrict__ bv,
    float* __restrict__ Q, float* __restrict__ K, float* __restrict__ V) {
    __shared__ float xs[128 * 129];
    __shared__ int sid[128];
    int tid = threadIdx.x;
    int b = blockIdx.x;
    // map block -> (type, slice of sorted[]) ; uniform across block
    int t = -1, p0 = 0;
    int cum = 0;
    for (int tt = 0; tt < NT; tt++) {
        int cnt_t = toff[tt + 1] - toff[tt];
        int nb = (cnt_t + 127) >> 7;
        if (t < 0 && b < cum + nb) { t = tt; p0 = toff[tt] + (b - cum) * 128; }
        cum += nb;
    }
    if (t < 0) return;
    int cnt = min(128, toff[t + 1] - p0);

    if (tid < 128) sid[tid] = (tid < cnt) ? sorted[p0 + tid] : -1;
    __syncthreads();
    // stage x rows (gathered) into LDS: 4096 float4 slots / 512 thr = 8 iters
    for (int j = 0; j < 8; j++) {
        int idx = j * 512 + tid;
        int row = idx >> 5, c4 = (idx & 31) * 4;
        int node = sid[row];
        if (node >= 0) {
            float4 v = *(const float4*)(x + (size_t)node * D + c4);
            float* p = &xs[row * 129 + c4];
            p[0] = v.x; p[1] = v.y; p[2] = v.z; p[3] = v.w;
        }
    }
    __syncthreads();

    int og = tid & 15, ng = tid >> 4;     // ng in 0..31 -> 4 nodes each
    int o0 = og * 8;
    const float* Ws[3] = {Wq + (size_t)t * D * D, Wk + (size_t)t * D * D, Wv + (size_t)t * D * D};
    const float* bs[3] = {bq + t * D, bk + t * D, bv + t * D};
    float* Os[3] = {Q, K, V};

    for (int m = 0; m < 3; m++) {
        const float* Wm = Ws[m];
        const float* bm = bs[m];
        float acc[4][8];
        float bias[8];
#pragma unroll
        for (int c = 0; c < 8; c++) bias[c] = bm[o0 + c];
#pragma unroll
        for (int r = 0; r < 4; r++)
#pragma unroll
            for (int c = 0; c < 8; c++) acc[r][c] = bias[c];

#pragma unroll 2
        for (int k = 0; k < D; k++) {
            float4 w0 = *(const float4*)(Wm + k * D + o0);
            float4 w1 = *(const float4*)(Wm + k * D + o0 + 4);
            float w8[8] = {w0.x, w0.y, w0.z, w0.w, w1.x, w1.y, w1.z, w1.w};
            float xv[4];
#pragma unroll
            for (int r = 0; r < 4; r++) xv[r] = xs[(ng * 4 + r) * 129 + k];
#pragma unroll
            for (int r = 0; r < 4; r++)
#pragma unroll
                for (int c = 0; c < 8; c++) acc[r][c] += xv[r] * w8[c];
        }
        float* Om = Os[m];
#pragma unroll
        for (int r = 0; r < 4; r++) {
            int node = sid[ng * 4 + r];
            if (node < 0) continue;
            float4 a0 = {acc[r][0], acc[r][1], acc[r][2], acc[r][3]};
            float4 a1 = {acc[r][4], acc[r][5], acc[r][6], acc[r][7]};
            *(float4*)(Om + (size_t)node * D + o0) = a0;
            *(float4*)(Om + (size_t)node * D + o0 + 4) = a1;
        }
    }
}

// ------------------------------- fused scores + softmax + aggregate + skip + LN
// One wave per dst node, flash-style online softmax over 8-edge chunks.
// Score pass: lane = h*8+li -> score(edge c0+li, head h), 16-dim dot in regs.
// Gather pass (R4): static-unrolled 8 -> 8 independent V loads in flight;
//   slots >= cn contribute exp(-inf)=0 with clamped (safe) addresses.
// Consume pass: lane owns dims {2*lane, 2*lane+1}, head = lane>>3.
__global__ __launch_bounds__(256) void k_agg(
    const int* __restrict__ row_ptr, const int* __restrict__ csr_rec,
    const int* __restrict__ nt, const float* __restrict__ x,
    const float* __restrict__ Qt, const float* __restrict__ Kt,
    const float* __restrict__ Vt, const float* __restrict__ rq,
    const float* __restrict__ rk, const float* __restrict__ rv,
    const float* __restrict__ skn, const float* __restrict__ svn,
    const float* __restrict__ rb, const float* __restrict__ skip,
    const float* __restrict__ gamma, const float* __restrict__ beta,
    float* __restrict__ out, int N) {
    // rel tables in LDS, row stride 132 (banks offset by 4*r => <=2-way, free)
    __shared__ float l_rq[NR * 132];
    __shared__ float l_rk[NR * 132];
    __shared__ float l_rv[NR * 132];
    __shared__ float l_rb[NR * NH];
    int tid = threadIdx.x;
    for (int idx = tid; idx < NR * D; idx += 256) {
        int r = idx >> 7, c = idx & 127;
        l_rq[r * 132 + c] = rq[idx];
        l_rk[r * 132 + c] = rk[idx];
        l_rv[r * 132 + c] = rv[idx];
    }
    if (tid < NR * NH) l_rb[tid] = rb[tid];
    __syncthreads();

    int wid = (blockIdx.x * 256 + tid) >> 6;
    if (wid >= N) return;
    int lane = tid & 63;
    int h = lane >> 3, li = lane & 7;
    int d0 = lane * 2;
    int dst = wid;
    int rp0 = row_ptr[dst];
    int deg = row_ptr[dst + 1] - rp0;

    // loop-invariant preloads
    float4 q4[4], sk4[4];
#pragma unroll
    for (int j = 0; j < 4; j++) {
        q4[j] = *(const float4*)(Qt + (size_t)dst * D + h * 16 + 4 * j);
        sk4[j] = *(const float4*)(skn + h * 16 + 4 * j);
    }
    float2 sv2 = *(const float2*)(svn + d0);
    float2 xi = *(const float2*)(x + (size_t)dst * D + d0);
    int t = nt[dst];

    float m = -INFINITY, lsum = 0.f, acc0 = 0.f, acc1 = 0.f;

    for (int c0 = 0; c0 < deg; c0 += 8) {
        int cn = min(8, deg - c0);
        // ---- score pass: lane (h, li) -> score(edge c0+li, head h)
        bool valid = li < cn;
        int recA = csr_rec[rp0 + c0 + (valid ? li : 0)];
        int srcA = recA & 0x1FFFF;
        int rA = (recA >> 17) & 7;
        int sgA = ((recA >> 20) & 3) - 1;
        bool neuA = (sgA == 0);
        float fsgA = (float)sgA;
        const float* kp = Kt + (size_t)srcA * D + h * 16;
        const float* rqp = &l_rq[rA * 132 + h * 16];
        const float* rkp = &l_rk[rA * 132 + h * 16];
        float dot = 0.f;
#pragma unroll
        for (int j = 0; j < 4; j++) {
            float4 k4 = *(const float4*)(kp + 4 * j);
            float4 a4 = *(const float4*)(rqp + 4 * j);
            float4 b4 = *(const float4*)(rkp + 4 * j);
            float f0 = neuA ? sk4[j].x : fsgA;
            float f1 = neuA ? sk4[j].y : fsgA;
            float f2 = neuA ? sk4[j].z : fsgA;
            float f3 = neuA ? sk4[j].w : fsgA;
            dot += q4[j].x * a4.x * k4.x * b4.x * f0;
            dot += q4[j].y * a4.y * k4.y * b4.y * f1;
            dot += q4[j].z * a4.z * k4.z * b4.z * f2;
            dot += q4[j].w * a4.w * k4.w * b4.w * f3;
        }
        float scA = valid ? dot * 0.25f + l_rb[rA * NH + h] : -INFINITY;
        // chunk max per head (reduce over li within the head group)
        float cm = scA;
        cm = fmaxf(cm, __shfl_xor(cm, 1));
        cm = fmaxf(cm, __shfl_xor(cm, 2));
        cm = fmaxf(cm, __shfl_xor(cm, 4));
        float nm = fmaxf(m, cm);
        float resc = __expf(m - nm);   // 0 on first chunk (m = -inf)
        acc0 *= resc; acc1 *= resc; lsum *= resc;
        m = nm;
        // ---- gather pass: static unroll -> 8 independent V loads in flight
        int rec_[8];
        float w_[8];
        float2 v2_[8];
#pragma unroll
        for (int i = 0; i < 8; i++) {
            rec_[i] = __shfl(recA, i);                    // edge i's record
            int src = rec_[i] & 0x1FFFF;
            v2_[i] = *(const float2*)(Vt + (size_t)src * D + d0);
            float s = __shfl(scA, (lane & 56) | i);       // score(i, my head)
            w_[i] = __expf(s - m);                        // 0 for i >= cn
        }
        // ---- consume pass: lane owns dims d0, d0+1 of head h
#pragma unroll
        for (int i = 0; i < 8; i++) {
            float w = w_[i];
            lsum += w;
            int r = (rec_[i] >> 17) & 7;
            int sg = ((rec_[i] >> 20) & 3) - 1;
            float2 r2 = *(const float2*)(&l_rv[r * 132 + d0]);
            bool neu = (sg == 0);
            float f0 = neu ? sv2.x : (float)sg;
            float f1 = neu ? sv2.y : (float)sg;
            acc0 += w * v2_[i].x * r2.x * f0;
            acc1 += w * v2_[i].y * r2.y * f1;
        }
    }
    float winv = 1.f / (lsum + 1e-16f);
    float a0 = acc0 * winv, a1 = acc1 * winv;

    // gated skip + layernorm epilogue
    float alpha = 1.f / (1.f + __expf(-skip[t]));
    float p0 = alpha * a0 + (1.f - alpha) * xi.x;
    float p1 = alpha * a1 + (1.f - alpha) * xi.y;
    float rs = p0 + p1, rsq = p0 * p0 + p1 * p1;
#pragma unroll
    for (int o = 1; o < 64; o <<= 1) {
        rs += __shfl_xor(rs, o);
        rsq += __shfl_xor(rsq, o);
    }
    float mu = rs * (1.f / 128.f);
    float var = rsq * (1.f / 128.f) - mu * mu;
    float rstd = rsqrtf(var + 1e-5f);
    float2 g2 = *(const float2*)(gamma + t * D + d0);
    float2 b2 = *(const float2*)(beta + t * D + d0);
    float o0 = (p0 - mu) * rstd * g2.x + b2.x;
    float o1 = (p1 - mu) * rstd * g2.y + b2.y;
    *(float2*)(out + (size_t)dst * D + d0) = make_float2(o0, o1);
}

// ---------------------------------------------------------------- launcher
extern "C" void kernel_launch(void* const* d_in, const int* in_sizes, int n_in,
                              void* d_out, int out_size, void* d_ws, size_t ws_size,
                              hipStream_t stream) {
    const float* x   = (const float*)d_in[0];
    const int*  nt   = (const int*)d_in[1];
    const int*  ei   = (const int*)d_in[2];
    const int*  et   = (const int*)d_in[3];
    const int*  es   = (const int*)d_in[4];
    const float* Wq  = (const float*)d_in[5];
    const float* bq  = (const float*)d_in[6];
    const float* Wk  = (const float*)d_in[7];
    const float* bk  = (const float*)d_in[8];
    const float* Wv  = (const float*)d_in[9];
    const float* bv  = (const float*)d_in[10];
    const float* rq  = (const float*)d_in[11];
    const float* rk  = (const float*)d_in[12];
    const float* rv  = (const float*)d_in[13];
    const float* skn = (const float*)d_in[14];
    const float* svn = (const float*)d_in[15];
    const float* rb  = (const float*)d_in[16];
    const float* skp = (const float*)d_in[17];
    const float* gma = (const float*)d_in[18];
    const float* bta = (const float*)d_in[19];
    float* out = (float*)d_out;

    int N = in_sizes[0] / D;   // 50000
    int E = in_sizes[2] / 2;   // 400000

    // workspace layout
    float* Q = (float*)d_ws;
    float* K = Q + (size_t)N * D;
    float* V = K + (size_t)N * D;
    int* deg     = (int*)(V + (size_t)N * D);
    int* tcnt    = deg + N;                       // 4
    int* tcur    = tcnt + NT;                     // 4
    int* row_ptr = tcur + NT;                     // N+1
    int* ecur    = row_ptr + N + 1;               // N
    int* toff    = ecur + N;                      // 5 (pad 8)
    int* sorted  = toff + 8;                      // N
    int* csr_rec = sorted + N;                    // E (packed records)

    // zero the atomic counters/histograms (deg | tcnt | tcur contiguous)
    hipMemsetAsync(deg, 0, (size_t)(N + 2 * NT) * sizeof(int), stream);

    int gbNE = (max(N, E) + 255) / 256;
    k_hist<<<gbNE, 256, 0, stream>>>(nt, ei, N, E, tcnt, deg);
    k_scan<<<1, 1024, 0, stream>>>(deg, tcnt, N, row_ptr, ecur, toff);
    k_scatter<<<gbNE, 256, 0, stream>>>(nt, ei, et, es, N, E, tcur, toff, sorted,
                                        ecur, csr_rec);
    k_proj<<<(N + 127) / 128 + NT, 512, 0, stream>>>(x, sorted, toff, Wq, bq, Wk, bk,
                                                     Wv, bv, Q, K, V);
    k_agg<<<(N * 64 + 255) / 256, 256, 0, stream>>>(row_ptr, csr_rec, nt, x, Q, K, V,
                                                    rq, rk, rv, skn, svn, rb, skp,
                                                    gma, bta, out, N);
}

// Round 7
// 353.011 us; speedup vs baseline: 2.8283x; 1.3112x over previous
//
#include <hip/hip_runtime.h>
#include <hip/hip_bf16.h>

// WeightedHGTConv: N=50000 nodes, E=400000 edges, D=128, T=4 types, R=8 rels,
// H=8 heads, DK=16.
// Pipeline: memset -> hist -> scan(x3, parallel) -> scatter(sort+pack) ->
//           proj(QKV, grid x3) -> fused agg
// R3: block-aggregated type counters (4-address atomic contention fix).
// R4: k_proj 512thr; k_agg static-unrolled gather (8 V loads in flight).
// R6: k_proj was 395 blocks on 256 CUs (load imbalance, VALUBusy 29%) ->
//     grid.y=3 (one matrix per block, 1185 blocks, bit-exact) + unroll 4;
//     single-block k_scan replaced by 3-kernel parallel scan.

#define D 128
#define NT 4
#define NR 8
#define NH 8
#define SCAN_BS 256

// ---------------------------------------------------------------- histogram
__global__ void k_hist(const int* __restrict__ nt, const int* __restrict__ ei,
                       int N, int E, int* __restrict__ tcnt, int* __restrict__ deg) {
    __shared__ int lcnt[NT];
    int tid = threadIdx.x;
    if (tid < NT) lcnt[tid] = 0;
    __syncthreads();
    int g = blockIdx.x * 256 + tid;
    if (g < N) atomicAdd(&lcnt[nt[g]], 1);              // LDS, cheap
    if (g < E) atomicAdd(&deg[ei[E + g]], 1);           // 50k counters, fire&forget
    __syncthreads();
    if (tid < NT && lcnt[tid]) atomicAdd(&tcnt[tid], lcnt[tid]);  // 4/block
}

// ------------------------------------------------- scan stage 1: block sums
__global__ __launch_bounds__(SCAN_BS) void k_scan1(const int* __restrict__ deg, int N,
                                                   int* __restrict__ bsum) {
    __shared__ int lds[SCAN_BS];
    int ti = threadIdx.x;
    int i = blockIdx.x * SCAN_BS + ti;
    lds[ti] = (i < N) ? deg[i] : 0;
    __syncthreads();
    for (int off = SCAN_BS >> 1; off > 0; off >>= 1) {
        if (ti < off) lds[ti] += lds[ti + off];
        __syncthreads();
    }
    if (ti == 0) bsum[blockIdx.x] = lds[0];
}

// --------------------------------- scan stage 2: scan block sums (1 block)
// NB <= SCAN_BS by construction (N <= 65536).
__global__ __launch_bounds__(SCAN_BS) void k_scan2(const int* __restrict__ bsum, int NB,
                                                   const int* __restrict__ tcnt,
                                                   int* __restrict__ bbase,
                                                   int* __restrict__ toff,
                                                   int* __restrict__ row_ptr, int N, int E) {
    __shared__ int lds[SCAN_BS];
    int ti = threadIdx.x;
    int v = (ti < NB) ? bsum[ti] : 0;
    lds[ti] = v;
    __syncthreads();
    for (int off = 1; off < SCAN_BS; off <<= 1) {
        int t = (ti >= off) ? lds[ti - off] : 0;
        __syncthreads();
        lds[ti] += t;
        __syncthreads();
    }
    if (ti < NB) bbase[ti] = lds[ti] - v;   // exclusive block base
    if (ti == 0) {
        int a = 0;
        for (int t = 0; t < NT; t++) { toff[t] = a; a += tcnt[t]; }
        toff[NT] = a;
        row_ptr[N] = E;
    }
}

// --------------------------------- scan stage 3: within-block exclusive scan
__global__ __launch_bounds__(SCAN_BS) void k_scan3(const int* __restrict__ deg, int N,
                                                   const int* __restrict__ bbase,
                                                   int* __restrict__ row_ptr,
                                                   int* __restrict__ ecur) {
    __shared__ int lds[SCAN_BS];
    int ti = threadIdx.x;
    int i = blockIdx.x * SCAN_BS + ti;
    int v = (i < N) ? deg[i] : 0;
    lds[ti] = v;
    __syncthreads();
    for (int off = 1; off < SCAN_BS; off <<= 1) {
        int t = (ti >= off) ? lds[ti - off] : 0;
        __syncthreads();
        lds[ti] += t;
        __syncthreads();
    }
    if (i < N) {
        int ex = bbase[blockIdx.x] + lds[ti] - v;
        row_ptr[i] = ex;
        ecur[i] = ex;
    }
}

// ------------------------------------------- scatter (counting sorts + edge pack)
// Node half: LDS rank within block + one global atomic per (block,type).
// Edge half: CSR slot gets packed record: src | (rel<<17) | ((sign+1)<<20).
__global__ void k_scatter(const int* __restrict__ nt, const int* __restrict__ ei,
                          const int* __restrict__ et, const int* __restrict__ es,
                          int N, int E, int* __restrict__ tcur,
                          const int* __restrict__ toff, int* __restrict__ sorted,
                          int* __restrict__ ecur, int* __restrict__ csr_rec) {
    __shared__ int lcnt[NT];
    __shared__ int lbase[NT];
    int tid = threadIdx.x;
    if (tid < NT) lcnt[tid] = 0;
    __syncthreads();
    int g = blockIdx.x * 256 + tid;
    int t = -1, myrank = 0;
    if (g < N) {
        t = nt[g];
        myrank = atomicAdd(&lcnt[t], 1);                // LDS-speed rank
    }
    __syncthreads();
    if (tid < NT) lbase[tid] = lcnt[tid] ? atomicAdd(&tcur[tid], lcnt[tid]) : 0;
    __syncthreads();
    if (t >= 0) sorted[toff[t] + lbase[t] + myrank] = g;

    if (g < E) {
        int src = ei[g];
        int d = ei[E + g];
        int r = et[g];
        int sg = es[g];
        int p = atomicAdd(&ecur[d], 1);                 // 50k counters, ~8-way
        csr_rec[p] = src | (r << 17) | ((sg + 1) << 20);
    }
}

// ---------------------------------------------------------------- projections
// Block = 512 thr, 128 (type-uniform, sorted) nodes, ONE matrix (blockIdx.y
// selects Q/K/V) — R6: 1185 balanced blocks instead of 395 (was 1.5 blk/CU).
// x tile in LDS (stride 129). Thread = 4 nodes x 8 outs register tile.
__global__ __launch_bounds__(512, 4) void k_proj(
    const float* __restrict__ x, const int* __restrict__ sorted,
    const int* __restrict__ toff,
    const float* __restrict__ Wq, const float* __restrict__ bq,
    const float* __restrict__ Wk, const float* __restrict__ bk,
    const float* __restrict__ Wv, const float* __restrict__ bv,
    float* __restrict__ Q, float* __restrict__ K, float* __restrict__ V) {
    __shared__ float xs[128 * 129];
    __shared__ int sid[128];
    int tid = threadIdx.x;
    int b = blockIdx.x;
    // map block -> (type, slice of sorted[]) ; uniform across block
    int t = -1, p0 = 0;
    int cum = 0;
    for (int tt = 0; tt < NT; tt++) {
        int cnt_t = toff[tt + 1] - toff[tt];
        int nb = (cnt_t + 127) >> 7;
        if (t < 0 && b < cum + nb) { t = tt; p0 = toff[tt] + (b - cum) * 128; }
        cum += nb;
    }
    if (t < 0) return;
    int cnt = min(128, toff[t + 1] - p0);

    if (tid < 128) sid[tid] = (tid < cnt) ? sorted[p0 + tid] : -1;
    __syncthreads();
    // stage x rows (gathered) into LDS: 4096 float4 slots / 512 thr = 8 iters
    for (int j = 0; j < 8; j++) {
        int idx = j * 512 + tid;
        int row = idx >> 5, c4 = (idx & 31) * 4;
        int node = sid[row];
        if (node >= 0) {
            float4 v = *(const float4*)(x + (size_t)node * D + c4);
            float* p = &xs[row * 129 + c4];
            p[0] = v.x; p[1] = v.y; p[2] = v.z; p[3] = v.w;
        }
    }
    __syncthreads();

    int og = tid & 15, ng = tid >> 4;     // ng in 0..31 -> 4 nodes each
    int o0 = og * 8;
    int m = blockIdx.y;                   // 0:Q 1:K 2:V
    const float* Wm = (m == 0) ? Wq : (m == 1) ? Wk : Wv;
    const float* bm = (m == 0) ? bq : (m == 1) ? bk : bv;
    float* Om = (m == 0) ? Q : (m == 1) ? K : V;
    Wm += (size_t)t * D * D;
    bm += t * D;

    float acc[4][8];
    float bias[8];
#pragma unroll
    for (int c = 0; c < 8; c++) bias[c] = bm[o0 + c];
#pragma unroll
    for (int r = 0; r < 4; r++)
#pragma unroll
        for (int c = 0; c < 8; c++) acc[r][c] = bias[c];

#pragma unroll 4
    for (int k = 0; k < D; k++) {
        float4 w0 = *(const float4*)(Wm + k * D + o0);
        float4 w1 = *(const float4*)(Wm + k * D + o0 + 4);
        float w8[8] = {w0.x, w0.y, w0.z, w0.w, w1.x, w1.y, w1.z, w1.w};
        float xv[4];
#pragma unroll
        for (int r = 0; r < 4; r++) xv[r] = xs[(ng * 4 + r) * 129 + k];
#pragma unroll
        for (int r = 0; r < 4; r++)
#pragma unroll
            for (int c = 0; c < 8; c++) acc[r][c] += xv[r] * w8[c];
    }
#pragma unroll
    for (int r = 0; r < 4; r++) {
        int node = sid[ng * 4 + r];
        if (node < 0) continue;
        float4 a0 = {acc[r][0], acc[r][1], acc[r][2], acc[r][3]};
        float4 a1 = {acc[r][4], acc[r][5], acc[r][6], acc[r][7]};
        *(float4*)(Om + (size_t)node * D + o0) = a0;
        *(float4*)(Om + (size_t)node * D + o0 + 4) = a1;
    }
}

// ------------------------------- fused scores + softmax + aggregate + skip + LN
// One wave per dst node, flash-style online softmax over 8-edge chunks.
// Score pass: lane = h*8+li -> score(edge c0+li, head h), 16-dim dot in regs.
// Gather pass: static-unrolled 8 -> 8 independent V loads in flight;
//   slots >= cn contribute exp(-inf)=0 with clamped (safe) addresses.
// Consume pass: lane owns dims {2*lane, 2*lane+1}, head = lane>>3.
__global__ __launch_bounds__(256) void k_agg(
    const int* __restrict__ row_ptr, const int* __restrict__ csr_rec,
    const int* __restrict__ nt, const float* __restrict__ x,
    const float* __restrict__ Qt, const float* __restrict__ Kt,
    const float* __restrict__ Vt, const float* __restrict__ rq,
    const float* __restrict__ rk, const float* __restrict__ rv,
    const float* __restrict__ skn, const float* __restrict__ svn,
    const float* __restrict__ rb, const float* __restrict__ skip,
    const float* __restrict__ gamma, const float* __restrict__ beta,
    float* __restrict__ out, int N) {
    // rel tables in LDS, row stride 132 (banks offset by 4*r => <=2-way, free)
    __shared__ float l_rq[NR * 132];
    __shared__ float l_rk[NR * 132];
    __shared__ float l_rv[NR * 132];
    __shared__ float l_rb[NR * NH];
    int tid = threadIdx.x;
    for (int idx = tid; idx < NR * D; idx += 256) {
        int r = idx >> 7, c = idx & 127;
        l_rq[r * 132 + c] = rq[idx];
        l_rk[r * 132 + c] = rk[idx];
        l_rv[r * 132 + c] = rv[idx];
    }
    if (tid < NR * NH) l_rb[tid] = rb[tid];
    __syncthreads();

    int wid = (blockIdx.x * 256 + tid) >> 6;
    if (wid >= N) return;
    int lane = tid & 63;
    int h = lane >> 3, li = lane & 7;
    int d0 = lane * 2;
    int dst = wid;
    int rp0 = row_ptr[dst];
    int deg = row_ptr[dst + 1] - rp0;

    // loop-invariant preloads
    float4 q4[4], sk4[4];
#pragma unroll
    for (int j = 0; j < 4; j++) {
        q4[j] = *(const float4*)(Qt + (size_t)dst * D + h * 16 + 4 * j);
        sk4[j] = *(const float4*)(skn + h * 16 + 4 * j);
    }
    float2 sv2 = *(const float2*)(svn + d0);
    float2 xi = *(const float2*)(x + (size_t)dst * D + d0);
    int t = nt[dst];

    float m = -INFINITY, lsum = 0.f, acc0 = 0.f, acc1 = 0.f;

    for (int c0 = 0; c0 < deg; c0 += 8) {
        int cn = min(8, deg - c0);
        // ---- score pass: lane (h, li) -> score(edge c0+li, head h)
        bool valid = li < cn;
        int recA = csr_rec[rp0 + c0 + (valid ? li : 0)];
        int srcA = recA & 0x1FFFF;
        int rA = (recA >> 17) & 7;
        int sgA = ((recA >> 20) & 3) - 1;
        bool neuA = (sgA == 0);
        float fsgA = (float)sgA;
        const float* kp = Kt + (size_t)srcA * D + h * 16;
        const float* rqp = &l_rq[rA * 132 + h * 16];
        const float* rkp = &l_rk[rA * 132 + h * 16];
        float dot = 0.f;
#pragma unroll
        for (int j = 0; j < 4; j++) {
            float4 k4 = *(const float4*)(kp + 4 * j);
            float4 a4 = *(const float4*)(rqp + 4 * j);
            float4 b4 = *(const float4*)(rkp + 4 * j);
            float f0 = neuA ? sk4[j].x : fsgA;
            float f1 = neuA ? sk4[j].y : fsgA;
            float f2 = neuA ? sk4[j].z : fsgA;
            float f3 = neuA ? sk4[j].w : fsgA;
            dot += q4[j].x * a4.x * k4.x * b4.x * f0;
            dot += q4[j].y * a4.y * k4.y * b4.y * f1;
            dot += q4[j].z * a4.z * k4.z * b4.z * f2;
            dot += q4[j].w * a4.w * k4.w * b4.w * f3;
        }
        float scA = valid ? dot * 0.25f + l_rb[rA * NH + h] : -INFINITY;
        // chunk max per head (reduce over li within the head group)
        float cm = scA;
        cm = fmaxf(cm, __shfl_xor(cm, 1));
        cm = fmaxf(cm, __shfl_xor(cm, 2));
        cm = fmaxf(cm, __shfl_xor(cm, 4));
        float nm = fmaxf(m, cm);
        float resc = __expf(m - nm);   // 0 on first chunk (m = -inf)
        acc0 *= resc; acc1 *= resc; lsum *= resc;
        m = nm;
        // ---- gather pass: static unroll -> 8 independent V loads in flight
        int rec_[8];
        float w_[8];
        float2 v2_[8];
#pragma unroll
        for (int i = 0; i < 8; i++) {
            rec_[i] = __shfl(recA, i);                    // edge i's record
            int src = rec_[i] & 0x1FFFF;
            v2_[i] = *(const float2*)(Vt + (size_t)src * D + d0);
            float s = __shfl(scA, (lane & 56) | i);       // score(i, my head)
            w_[i] = __expf(s - m);                        // 0 for i >= cn
        }
        // ---- consume pass: lane owns dims d0, d0+1 of head h
#pragma unroll
        for (int i = 0; i < 8; i++) {
            float w = w_[i];
            lsum += w;
            int r = (rec_[i] >> 17) & 7;
            int sg = ((rec_[i] >> 20) & 3) - 1;
            float2 r2 = *(const float2*)(&l_rv[r * 132 + d0]);
            bool neu = (sg == 0);
            float f0 = neu ? sv2.x : (float)sg;
            float f1 = neu ? sv2.y : (float)sg;
            acc0 += w * v2_[i].x * r2.x * f0;
            acc1 += w * v2_[i].y * r2.y * f1;
        }
    }
    float winv = 1.f / (lsum + 1e-16f);
    float a0 = acc0 * winv, a1 = acc1 * winv;

    // gated skip + layernorm epilogue
    float alpha = 1.f / (1.f + __expf(-skip[t]));
    float p0 = alpha * a0 + (1.f - alpha) * xi.x;
    float p1 = alpha * a1 + (1.f - alpha) * xi.y;
    float rs = p0 + p1, rsq = p0 * p0 + p1 * p1;
#pragma unroll
    for (int o = 1; o < 64; o <<= 1) {
        rs += __shfl_xor(rs, o);
        rsq += __shfl_xor(rsq, o);
    }
    float mu = rs * (1.f / 128.f);
    float var = rsq * (1.f / 128.f) - mu * mu;
    float rstd = rsqrtf(var + 1e-5f);
    float2 g2 = *(const float2*)(gamma + t * D + d0);
    float2 b2 = *(const float2*)(beta + t * D + d0);
    float o0 = (p0 - mu) * rstd * g2.x + b2.x;
    float o1 = (p1 - mu) * rstd * g2.y + b2.y;
    *(float2*)(out + (size_t)dst * D + d0) = make_float2(o0, o1);
}

// ---------------------------------------------------------------- launcher
extern "C" void kernel_launch(void* const* d_in, const int* in_sizes, int n_in,
                              void* d_out, int out_size, void* d_ws, size_t ws_size,
                              hipStream_t stream) {
    const float* x   = (const float*)d_in[0];
    const int*  nt   = (const int*)d_in[1];
    const int*  ei   = (const int*)d_in[2];
    const int*  et   = (const int*)d_in[3];
    const int*  es   = (const int*)d_in[4];
    const float* Wq  = (const float*)d_in[5];
    const float* bq  = (const float*)d_in[6];
    const float* Wk  = (const float*)d_in[7];
    const float* bk  = (const float*)d_in[8];
    const float* Wv  = (const float*)d_in[9];
    const float* bv  = (const float*)d_in[10];
    const float* rq  = (const float*)d_in[11];
    const float* rk  = (const float*)d_in[12];
    const float* rv  = (const float*)d_in[13];
    const float* skn = (const float*)d_in[14];
    const float* svn = (const float*)d_in[15];
    const float* rb  = (const float*)d_in[16];
    const float* skp = (const float*)d_in[17];
    const float* gma = (const float*)d_in[18];
    const float* bta = (const float*)d_in[19];
    float* out = (float*)d_out;

    int N = in_sizes[0] / D;   // 50000
    int E = in_sizes[2] / 2;   // 400000
    int NB = (N + SCAN_BS - 1) / SCAN_BS;   // 196 scan blocks

    // workspace layout
    float* Q = (float*)d_ws;
    float* K = Q + (size_t)N * D;
    float* V = K + (size_t)N * D;
    int* deg     = (int*)(V + (size_t)N * D);
    int* tcnt    = deg + N;                       // 4
    int* tcur    = tcnt + NT;                     // 4
    int* row_ptr = tcur + NT;                     // N+1
    int* ecur    = row_ptr + N + 1;               // N
    int* toff    = ecur + N;                      // 5 (pad 8)
    int* sorted  = toff + 8;                      // N
    int* csr_rec = sorted + N;                    // E (packed records)
    int* bsum    = csr_rec + E;                   // NB
    int* bbase   = bsum + NB;                     // NB

    // zero the atomic counters/histograms (deg | tcnt | tcur contiguous)
    hipMemsetAsync(deg, 0, (size_t)(N + 2 * NT) * sizeof(int), stream);

    int gbNE = (max(N, E) + 255) / 256;
    k_hist<<<gbNE, 256, 0, stream>>>(nt, ei, N, E, tcnt, deg);
    k_scan1<<<NB, SCAN_BS, 0, stream>>>(deg, N, bsum);
    k_scan2<<<1, SCAN_BS, 0, stream>>>(bsum, NB, tcnt, bbase, toff, row_ptr, N, E);
    k_scan3<<<NB, SCAN_BS, 0, stream>>>(deg, N, bbase, row_ptr, ecur);
    k_scatter<<<gbNE, 256, 0, stream>>>(nt, ei, et, es, N, E, tcur, toff, sorted,
                                        ecur, csr_rec);
    int nbp = (N + 127) / 128 + NT;
    k_proj<<<dim3(nbp, 3), 512, 0, stream>>>(x, sorted, toff, Wq, bq, Wk, bk,
                                             Wv, bv, Q, K, V);
    k_agg<<<(N * 64 + 255) / 256, 256, 0, stream>>>(row_ptr, csr_rec, nt, x, Q, K, V,
                                                    rq, rk, rv, skn, svn, rb, skp,
                                                    gma, bta, out, N);
}

// Round 9
// 340.394 us; speedup vs baseline: 2.9332x; 1.0371x over previous
//
#include <hip/hip_runtime.h>
#include <hip/hip_bf16.h>

// WeightedHGTConv: N=50000 nodes, E=400000 edges, D=128, T=4 types, R=8 rels,
// H=8 heads, DK=16.
// Pipeline: memset -> hist(n,e) -> scan x3 -> scatter(n,e) -> proj -> fused agg
// R3: block-aggregated type counters. R4: 512thr proj, unrolled agg gather.
// R6: proj grid.y=3 (balance); parallel scan.
// R8: K,V stored bf16 (RNE write, exact read) -> agg gather bytes halved
//     (E*1KB -> E*0.5KB; this was agg's floor); hist/scatter split into
//     node/edge kernels for profile attribution.
// R9: resubmit of R8 (bench never ran — GPU acquisition timeout).

#define D 128
#define NT 4
#define NR 8
#define NH 8
#define SCAN_BS 256

typedef unsigned short ushort_t;
typedef unsigned int uint_t;

static __device__ __forceinline__ ushort_t f2bf(float f) {   // RNE
    uint_t u = __float_as_uint(f);
    return (ushort_t)((u + 0x7FFFu + ((u >> 16) & 1u)) >> 16);
}
static __device__ __forceinline__ float bf2f(ushort_t h) {
    return __uint_as_float(((uint_t)h) << 16);
}

// ---------------------------------------------------------------- histograms
__global__ void k_hist_n(const int* __restrict__ nt, int N, int* __restrict__ tcnt) {
    __shared__ int lcnt[NT];
    int tid = threadIdx.x;
    if (tid < NT) lcnt[tid] = 0;
    __syncthreads();
    int g = blockIdx.x * 256 + tid;
    if (g < N) atomicAdd(&lcnt[nt[g]], 1);
    __syncthreads();
    if (tid < NT && lcnt[tid]) atomicAdd(&tcnt[tid], lcnt[tid]);
}

__global__ void k_hist_e(const int* __restrict__ ei, int E, int* __restrict__ deg) {
    int g = blockIdx.x * 256 + threadIdx.x;
    if (g < E) atomicAdd(&deg[ei[E + g]], 1);           // 50k counters, fire&forget
}

// ------------------------------------------------- scan stage 1: block sums
__global__ __launch_bounds__(SCAN_BS) void k_scan1(const int* __restrict__ deg, int N,
                                                   int* __restrict__ bsum) {
    __shared__ int lds[SCAN_BS];
    int ti = threadIdx.x;
    int i = blockIdx.x * SCAN_BS + ti;
    lds[ti] = (i < N) ? deg[i] : 0;
    __syncthreads();
    for (int off = SCAN_BS >> 1; off > 0; off >>= 1) {
        if (ti < off) lds[ti] += lds[ti + off];
        __syncthreads();
    }
    if (ti == 0) bsum[blockIdx.x] = lds[0];
}

// --------------------------------- scan stage 2: scan block sums (1 block)
__global__ __launch_bounds__(SCAN_BS) void k_scan2(const int* __restrict__ bsum, int NB,
                                                   const int* __restrict__ tcnt,
                                                   int* __restrict__ bbase,
                                                   int* __restrict__ toff,
                                                   int* __restrict__ row_ptr, int N, int E) {
    __shared__ int lds[SCAN_BS];
    int ti = threadIdx.x;
    int v = (ti < NB) ? bsum[ti] : 0;
    lds[ti] = v;
    __syncthreads();
    for (int off = 1; off < SCAN_BS; off <<= 1) {
        int t = (ti >= off) ? lds[ti - off] : 0;
        __syncthreads();
        lds[ti] += t;
        __syncthreads();
    }
    if (ti < NB) bbase[ti] = lds[ti] - v;   // exclusive block base
    if (ti == 0) {
        int a = 0;
        for (int t = 0; t < NT; t++) { toff[t] = a; a += tcnt[t]; }
        toff[NT] = a;
        row_ptr[N] = E;
    }
}

// --------------------------------- scan stage 3: within-block exclusive scan
__global__ __launch_bounds__(SCAN_BS) void k_scan3(const int* __restrict__ deg, int N,
                                                   const int* __restrict__ bbase,
                                                   int* __restrict__ row_ptr,
                                                   int* __restrict__ ecur) {
    __shared__ int lds[SCAN_BS];
    int ti = threadIdx.x;
    int i = blockIdx.x * SCAN_BS + ti;
    int v = (i < N) ? deg[i] : 0;
    lds[ti] = v;
    __syncthreads();
    for (int off = 1; off < SCAN_BS; off <<= 1) {
        int t = (ti >= off) ? lds[ti - off] : 0;
        __syncthreads();
        lds[ti] += t;
        __syncthreads();
    }
    if (i < N) {
        int ex = bbase[blockIdx.x] + lds[ti] - v;
        row_ptr[i] = ex;
        ecur[i] = ex;
    }
}

// ------------------------------------------- scatter: node counting sort
__global__ void k_scat_n(const int* __restrict__ nt, int N, int* __restrict__ tcur,
                         const int* __restrict__ toff, int* __restrict__ sorted) {
    __shared__ int lcnt[NT];
    __shared__ int lbase[NT];
    int tid = threadIdx.x;
    if (tid < NT) lcnt[tid] = 0;
    __syncthreads();
    int g = blockIdx.x * 256 + tid;
    int t = -1, myrank = 0;
    if (g < N) {
        t = nt[g];
        myrank = atomicAdd(&lcnt[t], 1);                // LDS-speed rank
    }
    __syncthreads();
    if (tid < NT) lbase[tid] = lcnt[tid] ? atomicAdd(&tcur[tid], lcnt[tid]) : 0;
    __syncthreads();
    if (t >= 0) sorted[toff[t] + lbase[t] + myrank] = g;
}

// ------------------------------------------- scatter: edge CSR (packed rec)
// rec = src | (rel<<17) | ((sign+1)<<20)
__global__ void k_scat_e(const int* __restrict__ ei, const int* __restrict__ et,
                         const int* __restrict__ es, int E,
                         int* __restrict__ ecur, int* __restrict__ csr_rec) {
    int g = blockIdx.x * 256 + threadIdx.x;
    if (g < E) {
        int src = ei[g];
        int d = ei[E + g];
        int r = et[g];
        int sg = es[g];
        int p = atomicAdd(&ecur[d], 1);                 // 50k counters, ~8-way
        csr_rec[p] = src | (r << 17) | ((sg + 1) << 20);
    }
}

// ---------------------------------------------------------------- projections
// Block = 512 thr, 128 (type-uniform, sorted) nodes, one matrix (blockIdx.y).
// Q written fp32; K,V written bf16 (RNE) — R8.
__global__ __launch_bounds__(512, 4) void k_proj(
    const float* __restrict__ x, const int* __restrict__ sorted,
    const int* __restrict__ toff,
    const float* __restrict__ Wq, const float* __restrict__ bq,
    const float* __restrict__ Wk, const float* __restrict__ bk,
    const float* __restrict__ Wv, const float* __restrict__ bv,
    float* __restrict__ Q, ushort_t* __restrict__ Kb, ushort_t* __restrict__ Vb) {
    __shared__ float xs[128 * 129];
    __shared__ int sid[128];
    int tid = threadIdx.x;
    int b = blockIdx.x;
    // map block -> (type, slice of sorted[]) ; uniform across block
    int t = -1, p0 = 0;
    int cum = 0;
    for (int tt = 0; tt < NT; tt++) {
        int cnt_t = toff[tt + 1] - toff[tt];
        int nb = (cnt_t + 127) >> 7;
        if (t < 0 && b < cum + nb) { t = tt; p0 = toff[tt] + (b - cum) * 128; }
        cum += nb;
    }
    if (t < 0) return;
    int cnt = min(128, toff[t + 1] - p0);

    if (tid < 128) sid[tid] = (tid < cnt) ? sorted[p0 + tid] : -1;
    __syncthreads();
    // stage x rows (gathered) into LDS: 4096 float4 slots / 512 thr = 8 iters
    for (int j = 0; j < 8; j++) {
        int idx = j * 512 + tid;
        int row = idx >> 5, c4 = (idx & 31) * 4;
        int node = sid[row];
        if (node >= 0) {
            float4 v = *(const float4*)(x + (size_t)node * D + c4);
            float* p = &xs[row * 129 + c4];
            p[0] = v.x; p[1] = v.y; p[2] = v.z; p[3] = v.w;
        }
    }
    __syncthreads();

    int og = tid & 15, ng = tid >> 4;     // ng in 0..31 -> 4 nodes each
    int o0 = og * 8;
    int m = blockIdx.y;                   // 0:Q 1:K 2:V
    const float* Wm = (m == 0) ? Wq : (m == 1) ? Wk : Wv;
    const float* bm = (m == 0) ? bq : (m == 1) ? bk : bv;
    Wm += (size_t)t * D * D;
    bm += t * D;

    float acc[4][8];
    float bias[8];
#pragma unroll
    for (int c = 0; c < 8; c++) bias[c] = bm[o0 + c];
#pragma unroll
    for (int r = 0; r < 4; r++)
#pragma unroll
        for (int c = 0; c < 8; c++) acc[r][c] = bias[c];

#pragma unroll 4
    for (int k = 0; k < D; k++) {
        float4 w0 = *(const float4*)(Wm + k * D + o0);
        float4 w1 = *(const float4*)(Wm + k * D + o0 + 4);
        float w8[8] = {w0.x, w0.y, w0.z, w0.w, w1.x, w1.y, w1.z, w1.w};
        float xv[4];
#pragma unroll
        for (int r = 0; r < 4; r++) xv[r] = xs[(ng * 4 + r) * 129 + k];
#pragma unroll
        for (int r = 0; r < 4; r++)
#pragma unroll
            for (int c = 0; c < 8; c++) acc[r][c] += xv[r] * w8[c];
    }
#pragma unroll
    for (int r = 0; r < 4; r++) {
        int node = sid[ng * 4 + r];
        if (node < 0) continue;
        if (m == 0) {
            float4 a0 = {acc[r][0], acc[r][1], acc[r][2], acc[r][3]};
            float4 a1 = {acc[r][4], acc[r][5], acc[r][6], acc[r][7]};
            *(float4*)(Q + (size_t)node * D + o0) = a0;
            *(float4*)(Q + (size_t)node * D + o0 + 4) = a1;
        } else {
            ushort_t* Om = (m == 1) ? Kb : Vb;
            uint_t p[4];
#pragma unroll
            for (int c = 0; c < 4; c++)
                p[c] = (uint_t)f2bf(acc[r][2 * c]) | ((uint_t)f2bf(acc[r][2 * c + 1]) << 16);
            uint4 pk = {p[0], p[1], p[2], p[3]};
            *(uint4*)(Om + (size_t)node * D + o0) = pk;   // 8 bf16 = 16B
        }
    }
}

// ------------------------------- fused scores + softmax + aggregate + skip + LN
// One wave per dst node, flash-style online softmax over 8-edge chunks.
// Score pass: lane = h*8+li -> score(edge c0+li, head h); K read as bf16 (32B).
// Gather pass: 8 independent V (bf16, 4B/lane) loads in flight.
// Consume pass: lane owns dims {2*lane, 2*lane+1}, head = lane>>3.
__global__ __launch_bounds__(256) void k_agg(
    const int* __restrict__ row_ptr, const int* __restrict__ csr_rec,
    const int* __restrict__ nt, const float* __restrict__ x,
    const float* __restrict__ Qt, const ushort_t* __restrict__ Kb,
    const ushort_t* __restrict__ Vb, const float* __restrict__ rq,
    const float* __restrict__ rk, const float* __restrict__ rv,
    const float* __restrict__ skn, const float* __restrict__ svn,
    const float* __restrict__ rb, const float* __restrict__ skip,
    const float* __restrict__ gamma, const float* __restrict__ beta,
    float* __restrict__ out, int N) {
    // rel tables in LDS, row stride 132 (banks offset by 4*r => <=2-way, free)
    __shared__ float l_rq[NR * 132];
    __shared__ float l_rk[NR * 132];
    __shared__ float l_rv[NR * 132];
    __shared__ float l_rb[NR * NH];
    int tid = threadIdx.x;
    for (int idx = tid; idx < NR * D; idx += 256) {
        int r = idx >> 7, c = idx & 127;
        l_rq[r * 132 + c] = rq[idx];
        l_rk[r * 132 + c] = rk[idx];
        l_rv[r * 132 + c] = rv[idx];
    }
    if (tid < NR * NH) l_rb[tid] = rb[tid];
    __syncthreads();

    int wid = (blockIdx.x * 256 + tid) >> 6;
    if (wid >= N) return;
    int lane = tid & 63;
    int h = lane >> 3, li = lane & 7;
    int d0 = lane * 2;
    int dst = wid;
    int rp0 = row_ptr[dst];
    int deg = row_ptr[dst + 1] - rp0;

    // loop-invariant preloads
    float4 q4[4], sk4[4];
#pragma unroll
    for (int j = 0; j < 4; j++) {
        q4[j] = *(const float4*)(Qt + (size_t)dst * D + h * 16 + 4 * j);
        sk4[j] = *(const float4*)(skn + h * 16 + 4 * j);
    }
    float2 sv2 = *(const float2*)(svn + d0);
    float2 xi = *(const float2*)(x + (size_t)dst * D + d0);
    int t = nt[dst];

    float m = -INFINITY, lsum = 0.f, acc0 = 0.f, acc1 = 0.f;

    for (int c0 = 0; c0 < deg; c0 += 8) {
        int cn = min(8, deg - c0);
        // ---- score pass: lane (h, li) -> score(edge c0+li, head h)
        bool valid = li < cn;
        int recA = csr_rec[rp0 + c0 + (valid ? li : 0)];
        int srcA = recA & 0x1FFFF;
        int rA = (recA >> 17) & 7;
        int sgA = ((recA >> 20) & 3) - 1;
        bool neuA = (sgA == 0);
        float fsgA = (float)sgA;
        const ushort_t* kp = Kb + (size_t)srcA * D + h * 16;
        const float* rqp = &l_rq[rA * 132 + h * 16];
        const float* rkp = &l_rk[rA * 132 + h * 16];
        float dot = 0.f;
#pragma unroll
        for (int j = 0; j < 4; j++) {
            ushort4 kk = ((const ushort4*)kp)[j];         // 4 bf16 = 8B
            float k0 = bf2f(kk.x), k1 = bf2f(kk.y), k2 = bf2f(kk.z), k3 = bf2f(kk.w);
            float4 a4 = *(const float4*)(rqp + 4 * j);
            float4 b4 = *(const float4*)(rkp + 4 * j);
            float f0 = neuA ? sk4[j].x : fsgA;
            float f1 = neuA ? sk4[j].y : fsgA;
            float f2 = neuA ? sk4[j].z : fsgA;
            float f3 = neuA ? sk4[j].w : fsgA;
            dot += q4[j].x * a4.x * k0 * b4.x * f0;
            dot += q4[j].y * a4.y * k1 * b4.y * f1;
            dot += q4[j].z * a4.z * k2 * b4.z * f2;
            dot += q4[j].w * a4.w * k3 * b4.w * f3;
        }
        float scA = valid ? dot * 0.25f + l_rb[rA * NH + h] : -INFINITY;
        // chunk max per head (reduce over li within the head group)
        float cm = scA;
        cm = fmaxf(cm, __shfl_xor(cm, 1));
        cm = fmaxf(cm, __shfl_xor(cm, 2));
        cm = fmaxf(cm, __shfl_xor(cm, 4));
        float nm = fmaxf(m, cm);
        float resc = __expf(m - nm);   // 0 on first chunk (m = -inf)
        acc0 *= resc; acc1 *= resc; lsum *= resc;
        m = nm;
        // ---- gather pass: static unroll -> 8 independent V loads in flight
        int rec_[8];
        float w_[8];
        uint_t v2_[8];
#pragma unroll
        for (int i = 0; i < 8; i++) {
            rec_[i] = __shfl(recA, i);                    // edge i's record
            int src = rec_[i] & 0x1FFFF;
            v2_[i] = *(const uint_t*)(Vb + (size_t)src * D + d0);   // 2 bf16
            float s = __shfl(scA, (lane & 56) | i);       // score(i, my head)
            w_[i] = __expf(s - m);                        // 0 for i >= cn
        }
        // ---- consume pass: lane owns dims d0, d0+1 of head h
#pragma unroll
        for (int i = 0; i < 8; i++) {
            float w = w_[i];
            lsum += w;
            int r = (rec_[i] >> 17) & 7;
            int sg = ((rec_[i] >> 20) & 3) - 1;
            float v0 = bf2f((ushort_t)(v2_[i] & 0xFFFF));
            float v1 = bf2f((ushort_t)(v2_[i] >> 16));
            float2 r2 = *(const float2*)(&l_rv[r * 132 + d0]);
            bool neu = (sg == 0);
            float f0 = neu ? sv2.x : (float)sg;
            float f1 = neu ? sv2.y : (float)sg;
            acc0 += w * v0 * r2.x * f0;
            acc1 += w * v1 * r2.y * f1;
        }
    }
    float winv = 1.f / (lsum + 1e-16f);
    float a0 = acc0 * winv, a1 = acc1 * winv;

    // gated skip + layernorm epilogue
    float alpha = 1.f / (1.f + __expf(-skip[t]));
    float p0 = alpha * a0 + (1.f - alpha) * xi.x;
    float p1 = alpha * a1 + (1.f - alpha) * xi.y;
    float rs = p0 + p1, rsq = p0 * p0 + p1 * p1;
#pragma unroll
    for (int o = 1; o < 64; o <<= 1) {
        rs += __shfl_xor(rs, o);
        rsq += __shfl_xor(rsq, o);
    }
    float mu = rs * (1.f / 128.f);
    float var = rsq * (1.f / 128.f) - mu * mu;
    float rstd = rsqrtf(var + 1e-5f);
    float2 g2 = *(const float2*)(gamma + t * D + d0);
    float2 b2 = *(const float2*)(beta + t * D + d0);
    float o0 = (p0 - mu) * rstd * g2.x + b2.x;
    float o1 = (p1 - mu) * rstd * g2.y + b2.y;
    *(float2*)(out + (size_t)dst * D + d0) = make_float2(o0, o1);
}

// ---------------------------------------------------------------- launcher
extern "C" void kernel_launch(void* const* d_in, const int* in_sizes, int n_in,
                              void* d_out, int out_size, void* d_ws, size_t ws_size,
                              hipStream_t stream) {
    const float* x   = (const float*)d_in[0];
    const int*  nt   = (const int*)d_in[1];
    const int*  ei   = (const int*)d_in[2];
    const int*  et   = (const int*)d_in[3];
    const int*  es   = (const int*)d_in[4];
    const float* Wq  = (const float*)d_in[5];
    const float* bq  = (const float*)d_in[6];
    const float* Wk  = (const float*)d_in[7];
    const float* bk  = (const float*)d_in[8];
    const float* Wv  = (const float*)d_in[9];
    const float* bv  = (const float*)d_in[10];
    const float* rq  = (const float*)d_in[11];
    const float* rk  = (const float*)d_in[12];
    const float* rv  = (const float*)d_in[13];
    const float* skn = (const float*)d_in[14];
    const float* svn = (const float*)d_in[15];
    const float* rb  = (const float*)d_in[16];
    const float* skp = (const float*)d_in[17];
    const float* gma = (const float*)d_in[18];
    const float* bta = (const float*)d_in[19];
    float* out = (float*)d_out;

    int N = in_sizes[0] / D;   // 50000
    int E = in_sizes[2] / 2;   // 400000
    int NB = (N + SCAN_BS - 1) / SCAN_BS;   // 196 scan blocks

    // workspace layout
    float*    Q  = (float*)d_ws;
    ushort_t* Kb = (ushort_t*)(Q + (size_t)N * D);
    ushort_t* Vb = Kb + (size_t)N * D;
    int* deg     = (int*)(Vb + (size_t)N * D);    // N*D ushorts even -> aligned
    int* tcnt    = deg + N;                       // 4
    int* tcur    = tcnt + NT;                     // 4
    int* row_ptr = tcur + NT;                     // N+1
    int* ecur    = row_ptr + N + 1;               // N
    int* toff    = ecur + N;                      // 5 (pad 8)
    int* sorted  = toff + 8;                      // N
    int* csr_rec = sorted + N;                    // E (packed records)
    int* bsum    = csr_rec + E;                   // NB
    int* bbase   = bsum + NB;                     // NB

    // zero the atomic counters/histograms (deg | tcnt | tcur contiguous)
    hipMemsetAsync(deg, 0, (size_t)(N + 2 * NT) * sizeof(int), stream);

    int gbN = (N + 255) / 256;
    int gbE = (E + 255) / 256;
    k_hist_n<<<gbN, 256, 0, stream>>>(nt, N, tcnt);
    k_hist_e<<<gbE, 256, 0, stream>>>(ei, E, deg);
    k_scan1<<<NB, SCAN_BS, 0, stream>>>(deg, N, bsum);
    k_scan2<<<1, SCAN_BS, 0, stream>>>(bsum, NB, tcnt, bbase, toff, row_ptr, N, E);
    k_scan3<<<NB, SCAN_BS, 0, stream>>>(deg, N, bbase, row_ptr, ecur);
    k_scat_n<<<gbN, 256, 0, stream>>>(nt, N, tcur, toff, sorted);
    k_scat_e<<<gbE, 256, 0, stream>>>(ei, et, es, E, ecur, csr_rec);
    int nbp = (N + 127) / 128 + NT;
    k_proj<<<dim3(nbp, 3), 512, 0, stream>>>(x, sorted, toff, Wq, bq, Wk, bk,
                                             Wv, bv, Q, Kb, Vb);
    k_agg<<<(N * 64 + 255) / 256, 256, 0, stream>>>(row_ptr, csr_rec, nt, x, Q, Kb, Vb,
                                                    rq, rk, rv, skn, svn, rb, skp,
                                                    gma, bta, out, N);
}

// Round 10
// 330.099 us; speedup vs baseline: 3.0246x; 1.0312x over previous
//
#include <hip/hip_runtime.h>
#include <hip/hip_bf16.h>

// WeightedHGTConv: N=50000 nodes, E=400000 edges, D=128, T=4 types, R=8 rels,
// H=8 heads, DK=16.
// Pipeline: memset -> wprep -> hist -> scan x3 -> scatter -> xprep -> projm(MFMA)
//           -> fused agg
// R3: block-aggregated type counters. R4: unrolled agg gather. R6: parallel scan.
// R8: K,V stored bf16 (halved agg gather bytes).
// R10: projection via split-bf16 MFMA (x=x_hi+x_lo, W=W_hi+W_lo, 3 MFMA passes
//      ~= fp32 precision; vector-ALU proj was at its 38us VALU floor with 65%
//      latency gaps, MfmaUtil 0). Fragment loads are contiguous 16B global
//      reads (x pre-sorted + bf16-split by k_xprep; W transposed + split by
//      k_wprep). hist/scatter re-fused.

#define D 128
#define NT 4
#define NR 8
#define NH 8
#define SCAN_BS 256

typedef unsigned short ushort_t;
typedef unsigned int uint_t;
typedef __attribute__((ext_vector_type(8))) short short8v;   // 8 bf16 (4 VGPR)
typedef __attribute__((ext_vector_type(4))) float f32x4;

static __device__ __forceinline__ ushort_t f2bf(float f) {   // RNE
    uint_t u = __float_as_uint(f);
    return (ushort_t)((u + 0x7FFFu + ((u >> 16) & 1u)) >> 16);
}
static __device__ __forceinline__ float bf2f(ushort_t h) {
    return __uint_as_float(((uint_t)h) << 16);
}

// ---------------------------------------------------------------- histogram
__global__ void k_hist(const int* __restrict__ nt, const int* __restrict__ ei,
                       int N, int E, int* __restrict__ tcnt, int* __restrict__ deg) {
    __shared__ int lcnt[NT];
    int tid = threadIdx.x;
    if (tid < NT) lcnt[tid] = 0;
    __syncthreads();
    int g = blockIdx.x * 256 + tid;
    if (g < N) atomicAdd(&lcnt[nt[g]], 1);              // LDS, cheap
    if (g < E) atomicAdd(&deg[ei[E + g]], 1);           // 50k counters, fire&forget
    __syncthreads();
    if (tid < NT && lcnt[tid]) atomicAdd(&tcnt[tid], lcnt[tid]);  // 4/block
}

// ------------------------------------------------- scan stage 1: block sums
__global__ __launch_bounds__(SCAN_BS) void k_scan1(const int* __restrict__ deg, int N,
                                                   int* __restrict__ bsum) {
    __shared__ int lds[SCAN_BS];
    int ti = threadIdx.x;
    int i = blockIdx.x * SCAN_BS + ti;
    lds[ti] = (i < N) ? deg[i] : 0;
    __syncthreads();
    for (int off = SCAN_BS >> 1; off > 0; off >>= 1) {
        if (ti < off) lds[ti] += lds[ti + off];
        __syncthreads();
    }
    if (ti == 0) bsum[blockIdx.x] = lds[0];
}

// --------------------------------- scan stage 2: scan block sums (1 block)
__global__ __launch_bounds__(SCAN_BS) void k_scan2(const int* __restrict__ bsum, int NB,
                                                   const int* __restrict__ tcnt,
                                                   int* __restrict__ bbase,
                                                   int* __restrict__ toff,
                                                   int* __restrict__ row_ptr, int N, int E) {
    __shared__ int lds[SCAN_BS];
    int ti = threadIdx.x;
    int v = (ti < NB) ? bsum[ti] : 0;
    lds[ti] = v;
    __syncthreads();
    for (int off = 1; off < SCAN_BS; off <<= 1) {
        int t = (ti >= off) ? lds[ti - off] : 0;
        __syncthreads();
        lds[ti] += t;
        __syncthreads();
    }
    if (ti < NB) bbase[ti] = lds[ti] - v;   // exclusive block base
    if (ti == 0) {
        int a = 0;
        for (int t = 0; t < NT; t++) { toff[t] = a; a += tcnt[t]; }
        toff[NT] = a;
        row_ptr[N] = E;
    }
}

// --------------------------------- scan stage 3: within-block exclusive scan
__global__ __launch_bounds__(SCAN_BS) void k_scan3(const int* __restrict__ deg, int N,
                                                   const int* __restrict__ bbase,
                                                   int* __restrict__ row_ptr,
                                                   int* __restrict__ ecur) {
    __shared__ int lds[SCAN_BS];
    int ti = threadIdx.x;
    int i = blockIdx.x * SCAN_BS + ti;
    int v = (i < N) ? deg[i] : 0;
    lds[ti] = v;
    __syncthreads();
    for (int off = 1; off < SCAN_BS; off <<= 1) {
        int t = (ti >= off) ? lds[ti - off] : 0;
        __syncthreads();
        lds[ti] += t;
        __syncthreads();
    }
    if (i < N) {
        int ex = bbase[blockIdx.x] + lds[ti] - v;
        row_ptr[i] = ex;
        ecur[i] = ex;
    }
}

// ------------------------------------------- scatter (counting sorts + edge pack)
// Node half: LDS rank within block + one global atomic per (block,type).
// Edge half: CSR slot gets packed record: src | (rel<<17) | ((sign+1)<<20).
__global__ void k_scatter(const int* __restrict__ nt, const int* __restrict__ ei,
                          const int* __restrict__ et, const int* __restrict__ es,
                          int N, int E, int* __restrict__ tcur,
                          const int* __restrict__ toff, int* __restrict__ sorted,
                          int* __restrict__ ecur, int* __restrict__ csr_rec) {
    __shared__ int lcnt[NT];
    __shared__ int lbase[NT];
    int tid = threadIdx.x;
    if (tid < NT) lcnt[tid] = 0;
    __syncthreads();
    int g = blockIdx.x * 256 + tid;
    int t = -1, myrank = 0;
    if (g < N) {
        t = nt[g];
        myrank = atomicAdd(&lcnt[t], 1);                // LDS-speed rank
    }
    __syncthreads();
    if (tid < NT) lbase[tid] = lcnt[tid] ? atomicAdd(&tcur[tid], lcnt[tid]) : 0;
    __syncthreads();
    if (t >= 0) sorted[toff[t] + lbase[t] + myrank] = g;

    if (g < E) {
        int src = ei[g];
        int d = ei[E + g];
        int r = et[g];
        int sg = es[g];
        int p = atomicAdd(&ecur[d], 1);                 // 50k counters, ~8-way
        csr_rec[p] = src | (r << 17) | ((sg + 1) << 20);
    }
}

// ------------------------------------ W prep: transpose + bf16 split (hi/lo)
// in:  W[m][t][k][o] fp32 (3 separate pointers)
// out: wt_hi/wt_lo[((m*NT+t)*128+o)*128+k] bf16 — B-fragment-contiguous in k.
__global__ void k_wprep(const float* __restrict__ Wq, const float* __restrict__ Wk,
                        const float* __restrict__ Wv,
                        ushort_t* __restrict__ wt_hi, ushort_t* __restrict__ wt_lo) {
    int g = blockIdx.x * 256 + threadIdx.x;     // over 3*4*128*128 = 196608
    if (g >= 3 * NT * D * D) return;
    int o = g & 127;
    int k = (g >> 7) & 127;
    int t = (g >> 14) & 3;
    int m = g >> 16;
    const float* Wsel = (m == 0) ? Wq : (m == 1) ? Wk : Wv;
    float w = Wsel[((size_t)t * D + k) * D + o];        // coalesced in o
    ushort_t hi = f2bf(w);
    ushort_t lo = f2bf(w - bf2f(hi));
    size_t dst = (((size_t)(m * NT + t) * D) + o) * D + k;
    wt_hi[dst] = hi;
    wt_lo[dst] = lo;
}

// ------------------------------------ x prep: gather to sorted order + split
// out rows are in sorted[] order so proj A-fragment loads are sequential.
__global__ void k_xprep(const float* __restrict__ x, const int* __restrict__ sorted,
                        int N, ushort_t* __restrict__ xs_hi, ushort_t* __restrict__ xs_lo) {
    int g = blockIdx.x * 256 + threadIdx.x;     // over N*32 float4 slots
    if (g >= N * 32) return;
    int i = g >> 5;
    int c4 = (g & 31) * 4;
    int node = sorted[i];
    float4 v = *(const float4*)(x + (size_t)node * D + c4);
    ushort4 h, l;
    h.x = f2bf(v.x); l.x = f2bf(v.x - bf2f(h.x));
    h.y = f2bf(v.y); l.y = f2bf(v.y - bf2f(h.y));
    h.z = f2bf(v.z); l.z = f2bf(v.z - bf2f(h.z));
    h.w = f2bf(v.w); l.w = f2bf(v.w - bf2f(h.w));
    *(ushort4*)(xs_hi + (size_t)i * D + c4) = h;
    *(ushort4*)(xs_lo + (size_t)i * D + c4) = l;
}

// --------------------------------------------- projections via split-bf16 MFMA
// Block = 512 thr (8 waves as 2 row x 4 col), 128 sorted nodes x 128 outs,
// one matrix (blockIdx.y). Per wave: 4x2 C-tiles of 16x16, K-loop 4 steps of 32.
// acc += x_lo*w_hi + x_hi*w_lo + x_hi*w_hi  (lo*lo ~2^-18, dropped).
// A-frag: row=lane&15, k=(lane>>4)*8+j (contiguous 16B from xs_*).
// B-frag: col=lane&15, k same (contiguous 16B from wt_*).
// C/D: col=lane&15, row=(lane>>4)*4+reg  [m89-verified layout].
__global__ __launch_bounds__(512) void k_projm(
    const ushort_t* __restrict__ xs_hi, const ushort_t* __restrict__ xs_lo,
    const ushort_t* __restrict__ wt_hi, const ushort_t* __restrict__ wt_lo,
    const int* __restrict__ sorted, const int* __restrict__ toff,
    const float* __restrict__ bq, const float* __restrict__ bk,
    const float* __restrict__ bv,
    float* __restrict__ Q, ushort_t* __restrict__ Kb, ushort_t* __restrict__ Vb) {
    __shared__ int sid[128];
    int tid = threadIdx.x;
    int b = blockIdx.x;
    // map block -> (type, slice of sorted[]) ; uniform across block
    int t = -1, p0 = 0;
    int cum = 0;
    for (int tt = 0; tt < NT; tt++) {
        int cnt_t = toff[tt + 1] - toff[tt];
        int nb = (cnt_t + 127) >> 7;
        if (t < 0 && b < cum + nb) { t = tt; p0 = toff[tt] + (b - cum) * 128; }
        cum += nb;
    }
    if (t < 0) return;
    int tend = toff[t + 1];
    if (tid < 128) sid[tid] = (p0 + tid < tend) ? sorted[p0 + tid] : -1;
    __syncthreads();

    int w = tid >> 6, lane = tid & 63;
    int wr = w >> 2, wc = w & 3;                 // wave tile: 64 rows x 32 cols
    int l15 = lane & 15, kq = lane >> 4;         // kq*8 = k sub-offset
    int m = blockIdx.y;                          // 0:Q 1:K 2:V

    const ushort_t* wth = wt_hi + ((size_t)(m * NT + t) * D) * D;
    const ushort_t* wtl = wt_lo + ((size_t)(m * NT + t) * D) * D;

    f32x4 acc[4][2];
#pragma unroll
    for (int fa = 0; fa < 4; fa++)
#pragma unroll
        for (int fb = 0; fb < 2; fb++) acc[fa][fb] = 0.f;

#pragma unroll
    for (int k0 = 0; k0 < D; k0 += 32) {
        int kk = k0 + kq * 8;
        short8v ah[4], al[4];
#pragma unroll
        for (int fa = 0; fa < 4; fa++) {
            size_t row = (size_t)(p0 + wr * 64 + fa * 16 + l15);
            ah[fa] = *(const short8v*)(xs_hi + row * D + kk);
            al[fa] = *(const short8v*)(xs_lo + row * D + kk);
        }
        short8v bh[2], bl[2];
#pragma unroll
        for (int fb = 0; fb < 2; fb++) {
            size_t col = (size_t)(wc * 32 + fb * 16 + l15);
            bh[fb] = *(const short8v*)(wth + col * D + kk);
            bl[fb] = *(const short8v*)(wtl + col * D + kk);
        }
#pragma unroll
        for (int fa = 0; fa < 4; fa++)
#pragma unroll
            for (int fb = 0; fb < 2; fb++) {
                acc[fa][fb] = __builtin_amdgcn_mfma_f32_16x16x32_bf16(
                    al[fa], bh[fb], acc[fa][fb], 0, 0, 0);
                acc[fa][fb] = __builtin_amdgcn_mfma_f32_16x16x32_bf16(
                    ah[fa], bl[fb], acc[fa][fb], 0, 0, 0);
                acc[fa][fb] = __builtin_amdgcn_mfma_f32_16x16x32_bf16(
                    ah[fa], bh[fb], acc[fa][fb], 0, 0, 0);
            }
    }

    const float* bm = (m == 0) ? bq : (m == 1) ? bk : bv;
    bm += t * D;
    float bias0 = bm[wc * 32 + l15];
    float bias1 = bm[wc * 32 + 16 + l15];
#pragma unroll
    for (int fa = 0; fa < 4; fa++) {
#pragma unroll
        for (int reg = 0; reg < 4; reg++) {
            int local = wr * 64 + fa * 16 + kq * 4 + reg;
            int node = sid[local];
            if (node < 0) continue;
            float v0 = acc[fa][0][reg] + bias0;
            float v1 = acc[fa][1][reg] + bias1;
            int col0 = wc * 32 + l15;
            if (m == 0) {
                Q[(size_t)node * D + col0] = v0;
                Q[(size_t)node * D + col0 + 16] = v1;
            } else {
                ushort_t* Om = (m == 1) ? Kb : Vb;
                Om[(size_t)node * D + col0] = f2bf(v0);
                Om[(size_t)node * D + col0 + 16] = f2bf(v1);
            }
        }
    }
}

// ------------------------------- fused scores + softmax + aggregate + skip + LN
// One wave per dst node, flash-style online softmax over 8-edge chunks.
// (unchanged from R9 — measured good; K/V read as bf16)
__global__ __launch_bounds__(256) void k_agg(
    const int* __restrict__ row_ptr, const int* __restrict__ csr_rec,
    const int* __restrict__ nt, const float* __restrict__ x,
    const float* __restrict__ Qt, const ushort_t* __restrict__ Kb,
    const ushort_t* __restrict__ Vb, const float* __restrict__ rq,
    const float* __restrict__ rk, const float* __restrict__ rv,
    const float* __restrict__ skn, const float* __restrict__ svn,
    const float* __restrict__ rb, const float* __restrict__ skip,
    const float* __restrict__ gamma, const float* __restrict__ beta,
    float* __restrict__ out, int N) {
    __shared__ float l_rq[NR * 132];
    __shared__ float l_rk[NR * 132];
    __shared__ float l_rv[NR * 132];
    __shared__ float l_rb[NR * NH];
    int tid = threadIdx.x;
    for (int idx = tid; idx < NR * D; idx += 256) {
        int r = idx >> 7, c = idx & 127;
        l_rq[r * 132 + c] = rq[idx];
        l_rk[r * 132 + c] = rk[idx];
        l_rv[r * 132 + c] = rv[idx];
    }
    if (tid < NR * NH) l_rb[tid] = rb[tid];
    __syncthreads();

    int wid = (blockIdx.x * 256 + tid) >> 6;
    if (wid >= N) return;
    int lane = tid & 63;
    int h = lane >> 3, li = lane & 7;
    int d0 = lane * 2;
    int dst = wid;
    int rp0 = row_ptr[dst];
    int deg = row_ptr[dst + 1] - rp0;

    float4 q4[4], sk4[4];
#pragma unroll
    for (int j = 0; j < 4; j++) {
        q4[j] = *(const float4*)(Qt + (size_t)dst * D + h * 16 + 4 * j);
        sk4[j] = *(const float4*)(skn + h * 16 + 4 * j);
    }
    float2 sv2 = *(const float2*)(svn + d0);
    float2 xi = *(const float2*)(x + (size_t)dst * D + d0);
    int t = nt[dst];

    float m = -INFINITY, lsum = 0.f, acc0 = 0.f, acc1 = 0.f;

    for (int c0 = 0; c0 < deg; c0 += 8) {
        int cn = min(8, deg - c0);
        bool valid = li < cn;
        int recA = csr_rec[rp0 + c0 + (valid ? li : 0)];
        int srcA = recA & 0x1FFFF;
        int rA = (recA >> 17) & 7;
        int sgA = ((recA >> 20) & 3) - 1;
        bool neuA = (sgA == 0);
        float fsgA = (float)sgA;
        const ushort_t* kp = Kb + (size_t)srcA * D + h * 16;
        const float* rqp = &l_rq[rA * 132 + h * 16];
        const float* rkp = &l_rk[rA * 132 + h * 16];
        float dot = 0.f;
#pragma unroll
        for (int j = 0; j < 4; j++) {
            ushort4 kk = ((const ushort4*)kp)[j];
            float k0 = bf2f(kk.x), k1 = bf2f(kk.y), k2 = bf2f(kk.z), k3 = bf2f(kk.w);
            float4 a4 = *(const float4*)(rqp + 4 * j);
            float4 b4 = *(const float4*)(rkp + 4 * j);
            float f0 = neuA ? sk4[j].x : fsgA;
            float f1 = neuA ? sk4[j].y : fsgA;
            float f2 = neuA ? sk4[j].z : fsgA;
            float f3 = neuA ? sk4[j].w : fsgA;
            dot += q4[j].x * a4.x * k0 * b4.x * f0;
            dot += q4[j].y * a4.y * k1 * b4.y * f1;
            dot += q4[j].z * a4.z * k2 * b4.z * f2;
            dot += q4[j].w * a4.w * k3 * b4.w * f3;
        }
        float scA = valid ? dot * 0.25f + l_rb[rA * NH + h] : -INFINITY;
        float cm = scA;
        cm = fmaxf(cm, __shfl_xor(cm, 1));
        cm = fmaxf(cm, __shfl_xor(cm, 2));
        cm = fmaxf(cm, __shfl_xor(cm, 4));
        float nm = fmaxf(m, cm);
        float resc = __expf(m - nm);
        acc0 *= resc; acc1 *= resc; lsum *= resc;
        m = nm;
        int rec_[8];
        float w_[8];
        uint_t v2_[8];
#pragma unroll
        for (int i = 0; i < 8; i++) {
            rec_[i] = __shfl(recA, i);
            int src = rec_[i] & 0x1FFFF;
            v2_[i] = *(const uint_t*)(Vb + (size_t)src * D + d0);
            float s = __shfl(scA, (lane & 56) | i);
            w_[i] = __expf(s - m);
        }
#pragma unroll
        for (int i = 0; i < 8; i++) {
            float w = w_[i];
            lsum += w;
            int r = (rec_[i] >> 17) & 7;
            int sg = ((rec_[i] >> 20) & 3) - 1;
            float v0 = bf2f((ushort_t)(v2_[i] & 0xFFFF));
            float v1 = bf2f((ushort_t)(v2_[i] >> 16));
            float2 r2 = *(const float2*)(&l_rv[r * 132 + d0]);
            bool neu = (sg == 0);
            float f0 = neu ? sv2.x : (float)sg;
            float f1 = neu ? sv2.y : (float)sg;
            acc0 += w * v0 * r2.x * f0;
            acc1 += w * v1 * r2.y * f1;
        }
    }
    float winv = 1.f / (lsum + 1e-16f);
    float a0 = acc0 * winv, a1 = acc1 * winv;

    float alpha = 1.f / (1.f + __expf(-skip[t]));
    float p0 = alpha * a0 + (1.f - alpha) * xi.x;
    float p1 = alpha * a1 + (1.f - alpha) * xi.y;
    float rs = p0 + p1, rsq = p0 * p0 + p1 * p1;
#pragma unroll
    for (int o = 1; o < 64; o <<= 1) {
        rs += __shfl_xor(rs, o);
        rsq += __shfl_xor(rsq, o);
    }
    float mu = rs * (1.f / 128.f);
    float var = rsq * (1.f / 128.f) - mu * mu;
    float rstd = rsqrtf(var + 1e-5f);
    float2 g2 = *(const float2*)(gamma + t * D + d0);
    float2 b2 = *(const float2*)(beta + t * D + d0);
    float o0 = (p0 - mu) * rstd * g2.x + b2.x;
    float o1 = (p1 - mu) * rstd * g2.y + b2.y;
    *(float2*)(out + (size_t)dst * D + d0) = make_float2(o0, o1);
}

// ---------------------------------------------------------------- launcher
extern "C" void kernel_launch(void* const* d_in, const int* in_sizes, int n_in,
                              void* d_out, int out_size, void* d_ws, size_t ws_size,
                              hipStream_t stream) {
    const float* x   = (const float*)d_in[0];
    const int*  nt   = (const int*)d_in[1];
    const int*  ei   = (const int*)d_in[2];
    const int*  et   = (const int*)d_in[3];
    const int*  es   = (const int*)d_in[4];
    const float* Wq  = (const float*)d_in[5];
    const float* bq  = (const float*)d_in[6];
    const float* Wk  = (const float*)d_in[7];
    const float* bk  = (const float*)d_in[8];
    const float* Wv  = (const float*)d_in[9];
    const float* bv  = (const float*)d_in[10];
    const float* rq  = (const float*)d_in[11];
    const float* rk  = (const float*)d_in[12];
    const float* rv  = (const float*)d_in[13];
    const float* skn = (const float*)d_in[14];
    const float* svn = (const float*)d_in[15];
    const float* rb  = (const float*)d_in[16];
    const float* skp = (const float*)d_in[17];
    const float* gma = (const float*)d_in[18];
    const float* bta = (const float*)d_in[19];
    float* out = (float*)d_out;

    int N = in_sizes[0] / D;   // 50000
    int E = in_sizes[2] / 2;   // 400000
    int NB = (N + SCAN_BS - 1) / SCAN_BS;   // scan blocks

    // workspace layout (all bf16 arrays 16B-aligned by construction)
    float*    Q     = (float*)d_ws;                    // N*D f32
    ushort_t* Kb    = (ushort_t*)(Q + (size_t)N * D);  // N*D bf16
    ushort_t* Vb    = Kb + (size_t)N * D;              // N*D bf16
    ushort_t* xs_hi = Vb + (size_t)N * D;              // N*D bf16 (sorted order)
    ushort_t* xs_lo = xs_hi + (size_t)N * D;           // N*D bf16
    ushort_t* wt_hi = xs_lo + (size_t)N * D;           // 3*4*128*128 bf16
    ushort_t* wt_lo = wt_hi + (size_t)3 * NT * D * D;
    int* deg     = (int*)(wt_lo + (size_t)3 * NT * D * D);
    int* tcnt    = deg + N;                       // 4
    int* tcur    = tcnt + NT;                     // 4
    int* row_ptr = tcur + NT;                     // N+1
    int* ecur    = row_ptr + N + 1;               // N
    int* toff    = ecur + N;                      // 5 (pad 8)
    int* sorted  = toff + 8;                      // N
    int* csr_rec = sorted + N;                    // E (packed records)
    int* bsum    = csr_rec + E;                   // NB
    int* bbase   = bsum + NB;                     // NB

    hipMemsetAsync(deg, 0, (size_t)(N + 2 * NT) * sizeof(int), stream);

    int gbNE = (max(N, E) + 255) / 256;
    k_wprep<<<(3 * NT * D * D + 255) / 256, 256, 0, stream>>>(Wq, Wk, Wv, wt_hi, wt_lo);
    k_hist<<<gbNE, 256, 0, stream>>>(nt, ei, N, E, tcnt, deg);
    k_scan1<<<NB, SCAN_BS, 0, stream>>>(deg, N, bsum);
    k_scan2<<<1, SCAN_BS, 0, stream>>>(bsum, NB, tcnt, bbase, toff, row_ptr, N, E);
    k_scan3<<<NB, SCAN_BS, 0, stream>>>(deg, N, bbase, row_ptr, ecur);
    k_scatter<<<gbNE, 256, 0, stream>>>(nt, ei, et, es, N, E, tcur, toff, sorted,
                                        ecur, csr_rec);
    k_xprep<<<(N * 32 + 255) / 256, 256, 0, stream>>>(x, sorted, N, xs_hi, xs_lo);
    int nbp = (N + 127) / 128 + NT;
    k_projm<<<dim3(nbp, 3), 512, 0, stream>>>(xs_hi, xs_lo, wt_hi, wt_lo, sorted,
                                              toff, bq, bk, bv, Q, Kb, Vb);
    k_agg<<<(N * 64 + 255) / 256, 256, 0, stream>>>(row_ptr, csr_rec, nt, x, Q, Kb, Vb,
                                                    rq, rk, rv, skn, svn, rb, skp,
                                                    gma, bta, out, N);
}

// Round 11
// 310.482 us; speedup vs baseline: 3.2158x; 1.0632x over previous
//
#include <hip/hip_runtime.h>
#include <hip/hip_bf16.h>

// WeightedHGTConv: N=50000 nodes, E=400000 edges, D=128, T=4 types, R=8 rels,
// H=8 heads, DK=16.
// Pipeline: memset -> wprep -> hist -> scan x3 -> scatter -> xprep -> projm(MFMA)
//           -> fused agg
// R3: block-aggregated type counters. R4: unrolled agg gather. R6: parallel scan.
// R8: K,V stored bf16. R10: proj via split-bf16 MFMA (3 passes ~= fp32).
// R11: k_agg: (a) persistent grid-stride blocks (rel-table staging amortized
//      12.5k blocks -> 2048); (b) exp computed once per (edge,head) in score
//      layout, weight shuffled (was 8x redundant per lane); (c) uint4 K decode.

#define D 128
#define NT 4
#define NR 8
#define NH 8
#define SCAN_BS 256

typedef unsigned short ushort_t;
typedef unsigned int uint_t;
typedef __attribute__((ext_vector_type(8))) short short8v;   // 8 bf16 (4 VGPR)
typedef __attribute__((ext_vector_type(4))) float f32x4;

static __device__ __forceinline__ ushort_t f2bf(float f) {   // RNE
    uint_t u = __float_as_uint(f);
    return (ushort_t)((u + 0x7FFFu + ((u >> 16) & 1u)) >> 16);
}
static __device__ __forceinline__ float bf2f(ushort_t h) {
    return __uint_as_float(((uint_t)h) << 16);
}
static __device__ __forceinline__ float bflo(uint_t u) {     // low bf16 of packed pair
    return __uint_as_float(u << 16);
}
static __device__ __forceinline__ float bfhi(uint_t u) {     // high bf16
    return __uint_as_float(u & 0xFFFF0000u);
}

// ---------------------------------------------------------------- histogram
__global__ void k_hist(const int* __restrict__ nt, const int* __restrict__ ei,
                       int N, int E, int* __restrict__ tcnt, int* __restrict__ deg) {
    __shared__ int lcnt[NT];
    int tid = threadIdx.x;
    if (tid < NT) lcnt[tid] = 0;
    __syncthreads();
    int g = blockIdx.x * 256 + tid;
    if (g < N) atomicAdd(&lcnt[nt[g]], 1);              // LDS, cheap
    if (g < E) atomicAdd(&deg[ei[E + g]], 1);           // 50k counters, fire&forget
    __syncthreads();
    if (tid < NT && lcnt[tid]) atomicAdd(&tcnt[tid], lcnt[tid]);  // 4/block
}

// ------------------------------------------------- scan stage 1: block sums
__global__ __launch_bounds__(SCAN_BS) void k_scan1(const int* __restrict__ deg, int N,
                                                   int* __restrict__ bsum) {
    __shared__ int lds[SCAN_BS];
    int ti = threadIdx.x;
    int i = blockIdx.x * SCAN_BS + ti;
    lds[ti] = (i < N) ? deg[i] : 0;
    __syncthreads();
    for (int off = SCAN_BS >> 1; off > 0; off >>= 1) {
        if (ti < off) lds[ti] += lds[ti + off];
        __syncthreads();
    }
    if (ti == 0) bsum[blockIdx.x] = lds[0];
}

// --------------------------------- scan stage 2: scan block sums (1 block)
__global__ __launch_bounds__(SCAN_BS) void k_scan2(const int* __restrict__ bsum, int NB,
                                                   const int* __restrict__ tcnt,
                                                   int* __restrict__ bbase,
                                                   int* __restrict__ toff,
                                                   int* __restrict__ row_ptr, int N, int E) {
    __shared__ int lds[SCAN_BS];
    int ti = threadIdx.x;
    int v = (ti < NB) ? bsum[ti] : 0;
    lds[ti] = v;
    __syncthreads();
    for (int off = 1; off < SCAN_BS; off <<= 1) {
        int t = (ti >= off) ? lds[ti - off] : 0;
        __syncthreads();
        lds[ti] += t;
        __syncthreads();
    }
    if (ti < NB) bbase[ti] = lds[ti] - v;   // exclusive block base
    if (ti == 0) {
        int a = 0;
        for (int t = 0; t < NT; t++) { toff[t] = a; a += tcnt[t]; }
        toff[NT] = a;
        row_ptr[N] = E;
    }
}

// --------------------------------- scan stage 3: within-block exclusive scan
__global__ __launch_bounds__(SCAN_BS) void k_scan3(const int* __restrict__ deg, int N,
                                                   const int* __restrict__ bbase,
                                                   int* __restrict__ row_ptr,
                                                   int* __restrict__ ecur) {
    __shared__ int lds[SCAN_BS];
    int ti = threadIdx.x;
    int i = blockIdx.x * SCAN_BS + ti;
    int v = (i < N) ? deg[i] : 0;
    lds[ti] = v;
    __syncthreads();
    for (int off = 1; off < SCAN_BS; off <<= 1) {
        int t = (ti >= off) ? lds[ti - off] : 0;
        __syncthreads();
        lds[ti] += t;
        __syncthreads();
    }
    if (i < N) {
        int ex = bbase[blockIdx.x] + lds[ti] - v;
        row_ptr[i] = ex;
        ecur[i] = ex;
    }
}

// ------------------------------------------- scatter (counting sorts + edge pack)
__global__ void k_scatter(const int* __restrict__ nt, const int* __restrict__ ei,
                          const int* __restrict__ et, const int* __restrict__ es,
                          int N, int E, int* __restrict__ tcur,
                          const int* __restrict__ toff, int* __restrict__ sorted,
                          int* __restrict__ ecur, int* __restrict__ csr_rec) {
    __shared__ int lcnt[NT];
    __shared__ int lbase[NT];
    int tid = threadIdx.x;
    if (tid < NT) lcnt[tid] = 0;
    __syncthreads();
    int g = blockIdx.x * 256 + tid;
    int t = -1, myrank = 0;
    if (g < N) {
        t = nt[g];
        myrank = atomicAdd(&lcnt[t], 1);                // LDS-speed rank
    }
    __syncthreads();
    if (tid < NT) lbase[tid] = lcnt[tid] ? atomicAdd(&tcur[tid], lcnt[tid]) : 0;
    __syncthreads();
    if (t >= 0) sorted[toff[t] + lbase[t] + myrank] = g;

    if (g < E) {
        int src = ei[g];
        int d = ei[E + g];
        int r = et[g];
        int sg = es[g];
        int p = atomicAdd(&ecur[d], 1);                 // 50k counters, ~8-way
        csr_rec[p] = src | (r << 17) | ((sg + 1) << 20);
    }
}

// ------------------------------------ W prep: transpose + bf16 split (hi/lo)
__global__ void k_wprep(const float* __restrict__ Wq, const float* __restrict__ Wk,
                        const float* __restrict__ Wv,
                        ushort_t* __restrict__ wt_hi, ushort_t* __restrict__ wt_lo) {
    int g = blockIdx.x * 256 + threadIdx.x;     // over 3*4*128*128 = 196608
    if (g >= 3 * NT * D * D) return;
    int o = g & 127;
    int k = (g >> 7) & 127;
    int t = (g >> 14) & 3;
    int m = g >> 16;
    const float* Wsel = (m == 0) ? Wq : (m == 1) ? Wk : Wv;
    float w = Wsel[((size_t)t * D + k) * D + o];        // coalesced in o
    ushort_t hi = f2bf(w);
    ushort_t lo = f2bf(w - bf2f(hi));
    size_t dst = (((size_t)(m * NT + t) * D) + o) * D + k;
    wt_hi[dst] = hi;
    wt_lo[dst] = lo;
}

// ------------------------------------ x prep: gather to sorted order + split
__global__ void k_xprep(const float* __restrict__ x, const int* __restrict__ sorted,
                        int N, ushort_t* __restrict__ xs_hi, ushort_t* __restrict__ xs_lo) {
    int g = blockIdx.x * 256 + threadIdx.x;     // over N*32 float4 slots
    if (g >= N * 32) return;
    int i = g >> 5;
    int c4 = (g & 31) * 4;
    int node = sorted[i];
    float4 v = *(const float4*)(x + (size_t)node * D + c4);
    ushort4 h, l;
    h.x = f2bf(v.x); l.x = f2bf(v.x - bf2f(h.x));
    h.y = f2bf(v.y); l.y = f2bf(v.y - bf2f(h.y));
    h.z = f2bf(v.z); l.z = f2bf(v.z - bf2f(h.z));
    h.w = f2bf(v.w); l.w = f2bf(v.w - bf2f(h.w));
    *(ushort4*)(xs_hi + (size_t)i * D + c4) = h;
    *(ushort4*)(xs_lo + (size_t)i * D + c4) = l;
}

// --------------------------------------------- projections via split-bf16 MFMA
// (unchanged from R10 — measured good)
__global__ __launch_bounds__(512) void k_projm(
    const ushort_t* __restrict__ xs_hi, const ushort_t* __restrict__ xs_lo,
    const ushort_t* __restrict__ wt_hi, const ushort_t* __restrict__ wt_lo,
    const int* __restrict__ sorted, const int* __restrict__ toff,
    const float* __restrict__ bq, const float* __restrict__ bk,
    const float* __restrict__ bv,
    float* __restrict__ Q, ushort_t* __restrict__ Kb, ushort_t* __restrict__ Vb) {
    __shared__ int sid[128];
    int tid = threadIdx.x;
    int b = blockIdx.x;
    int t = -1, p0 = 0;
    int cum = 0;
    for (int tt = 0; tt < NT; tt++) {
        int cnt_t = toff[tt + 1] - toff[tt];
        int nb = (cnt_t + 127) >> 7;
        if (t < 0 && b < cum + nb) { t = tt; p0 = toff[tt] + (b - cum) * 128; }
        cum += nb;
    }
    if (t < 0) return;
    int tend = toff[t + 1];
    if (tid < 128) sid[tid] = (p0 + tid < tend) ? sorted[p0 + tid] : -1;
    __syncthreads();

    int w = tid >> 6, lane = tid & 63;
    int wr = w >> 2, wc = w & 3;                 // wave tile: 64 rows x 32 cols
    int l15 = lane & 15, kq = lane >> 4;
    int m = blockIdx.y;                          // 0:Q 1:K 2:V

    const ushort_t* wth = wt_hi + ((size_t)(m * NT + t) * D) * D;
    const ushort_t* wtl = wt_lo + ((size_t)(m * NT + t) * D) * D;

    f32x4 acc[4][2];
#pragma unroll
    for (int fa = 0; fa < 4; fa++)
#pragma unroll
        for (int fb = 0; fb < 2; fb++) acc[fa][fb] = 0.f;

#pragma unroll
    for (int k0 = 0; k0 < D; k0 += 32) {
        int kk = k0 + kq * 8;
        short8v ah[4], al[4];
#pragma unroll
        for (int fa = 0; fa < 4; fa++) {
            size_t row = (size_t)(p0 + wr * 64 + fa * 16 + l15);
            ah[fa] = *(const short8v*)(xs_hi + row * D + kk);
            al[fa] = *(const short8v*)(xs_lo + row * D + kk);
        }
        short8v bh[2], bl[2];
#pragma unroll
        for (int fb = 0; fb < 2; fb++) {
            size_t col = (size_t)(wc * 32 + fb * 16 + l15);
            bh[fb] = *(const short8v*)(wth + col * D + kk);
            bl[fb] = *(const short8v*)(wtl + col * D + kk);
        }
#pragma unroll
        for (int fa = 0; fa < 4; fa++)
#pragma unroll
            for (int fb = 0; fb < 2; fb++) {
                acc[fa][fb] = __builtin_amdgcn_mfma_f32_16x16x32_bf16(
                    al[fa], bh[fb], acc[fa][fb], 0, 0, 0);
                acc[fa][fb] = __builtin_amdgcn_mfma_f32_16x16x32_bf16(
                    ah[fa], bl[fb], acc[fa][fb], 0, 0, 0);
                acc[fa][fb] = __builtin_amdgcn_mfma_f32_16x16x32_bf16(
                    ah[fa], bh[fb], acc[fa][fb], 0, 0, 0);
            }
    }

    const float* bm = (m == 0) ? bq : (m == 1) ? bk : bv;
    bm += t * D;
    float bias0 = bm[wc * 32 + l15];
    float bias1 = bm[wc * 32 + 16 + l15];
#pragma unroll
    for (int fa = 0; fa < 4; fa++) {
#pragma unroll
        for (int reg = 0; reg < 4; reg++) {
            int local = wr * 64 + fa * 16 + kq * 4 + reg;
            int node = sid[local];
            if (node < 0) continue;
            float v0 = acc[fa][0][reg] + bias0;
            float v1 = acc[fa][1][reg] + bias1;
            int col0 = wc * 32 + l15;
            if (m == 0) {
                Q[(size_t)node * D + col0] = v0;
                Q[(size_t)node * D + col0 + 16] = v1;
            } else {
                ushort_t* Om = (m == 1) ? Kb : Vb;
                Om[(size_t)node * D + col0] = f2bf(v0);
                Om[(size_t)node * D + col0 + 16] = f2bf(v1);
            }
        }
    }
}

// ------------------------------- fused scores + softmax + aggregate + skip + LN
// R11: persistent grid-stride blocks (stage rel tables once per block, process
// ~24 dsts); exp once per (edge,head) in score layout, weight shuffled;
// K decoded from uint4 (and/shl bf16 decode).
__global__ __launch_bounds__(256) void k_agg(
    const int* __restrict__ row_ptr, const int* __restrict__ csr_rec,
    const int* __restrict__ nt, const float* __restrict__ x,
    const float* __restrict__ Qt, const ushort_t* __restrict__ Kb,
    const ushort_t* __restrict__ Vb, const float* __restrict__ rq,
    const float* __restrict__ rk, const float* __restrict__ rv,
    const float* __restrict__ skn, const float* __restrict__ svn,
    const float* __restrict__ rb, const float* __restrict__ skip,
    const float* __restrict__ gamma, const float* __restrict__ beta,
    float* __restrict__ out, int N) {
    __shared__ float l_rq[NR * 132];
    __shared__ float l_rk[NR * 132];
    __shared__ float l_rv[NR * 132];
    __shared__ float l_rb[NR * NH];
    int tid = threadIdx.x;
    for (int idx = tid; idx < NR * D; idx += 256) {
        int r = idx >> 7, c = idx & 127;
        l_rq[r * 132 + c] = rq[idx];
        l_rk[r * 132 + c] = rk[idx];
        l_rv[r * 132 + c] = rv[idx];
    }
    if (tid < NR * NH) l_rb[tid] = rb[tid];
    __syncthreads();

    int lane = tid & 63;
    int h = lane >> 3, li = lane & 7;
    int d0 = lane * 2;

    // per-lane loop-invariant preloads (constant across dsts)
    float4 sk4[4];
#pragma unroll
    for (int j = 0; j < 4; j++) sk4[j] = *(const float4*)(skn + h * 16 + 4 * j);
    float2 sv2 = *(const float2*)(svn + d0);

    int wid0 = (blockIdx.x * 256 + tid) >> 6;
    int wstride = (gridDim.x * 256) >> 6;

    for (int dst = wid0; dst < N; dst += wstride) {
        int rp0 = row_ptr[dst];
        int deg = row_ptr[dst + 1] - rp0;
        float4 q4[4];
#pragma unroll
        for (int j = 0; j < 4; j++)
            q4[j] = *(const float4*)(Qt + (size_t)dst * D + h * 16 + 4 * j);
        float2 xi = *(const float2*)(x + (size_t)dst * D + d0);
        int t = nt[dst];

        float m = -INFINITY, lsum = 0.f, acc0 = 0.f, acc1 = 0.f;

        for (int c0 = 0; c0 < deg; c0 += 8) {
            int cn = min(8, deg - c0);
            // ---- score pass: lane (h, li) -> score(edge c0+li, head h)
            bool valid = li < cn;
            int recA = csr_rec[rp0 + c0 + (valid ? li : 0)];
            int srcA = recA & 0x1FFFF;
            int rA = (recA >> 17) & 7;
            int sgA = ((recA >> 20) & 3) - 1;
            bool neuA = (sgA == 0);
            float fsgA = (float)sgA;
            const uint4* kp4 = (const uint4*)(Kb + (size_t)srcA * D + h * 16);
            uint4 kA = kp4[0], kB = kp4[1];               // 16 bf16
            float ke[16];
            ke[0] = bflo(kA.x); ke[1] = bfhi(kA.x);
            ke[2] = bflo(kA.y); ke[3] = bfhi(kA.y);
            ke[4] = bflo(kA.z); ke[5] = bfhi(kA.z);
            ke[6] = bflo(kA.w); ke[7] = bfhi(kA.w);
            ke[8] = bflo(kB.x); ke[9] = bfhi(kB.x);
            ke[10] = bflo(kB.y); ke[11] = bfhi(kB.y);
            ke[12] = bflo(kB.z); ke[13] = bfhi(kB.z);
            ke[14] = bflo(kB.w); ke[15] = bfhi(kB.w);
            const float* rqp = &l_rq[rA * 132 + h * 16];
            const float* rkp = &l_rk[rA * 132 + h * 16];
            float dot = 0.f;
#pragma unroll
            for (int j = 0; j < 4; j++) {
                float4 a4 = *(const float4*)(rqp + 4 * j);
                float4 b4 = *(const float4*)(rkp + 4 * j);
                float f0 = neuA ? sk4[j].x : fsgA;
                float f1 = neuA ? sk4[j].y : fsgA;
                float f2 = neuA ? sk4[j].z : fsgA;
                float f3 = neuA ? sk4[j].w : fsgA;
                dot += q4[j].x * a4.x * ke[4 * j] * b4.x * f0;
                dot += q4[j].y * a4.y * ke[4 * j + 1] * b4.y * f1;
                dot += q4[j].z * a4.z * ke[4 * j + 2] * b4.z * f2;
                dot += q4[j].w * a4.w * ke[4 * j + 3] * b4.w * f3;
            }
            float scA = valid ? dot * 0.25f + l_rb[rA * NH + h] : -INFINITY;
            // chunk max per head, online rescale
            float cm = scA;
            cm = fmaxf(cm, __shfl_xor(cm, 1));
            cm = fmaxf(cm, __shfl_xor(cm, 2));
            cm = fmaxf(cm, __shfl_xor(cm, 4));
            float nm = fmaxf(m, cm);
            float resc = __expf(m - nm);   // 0 on first chunk
            acc0 *= resc; acc1 *= resc; lsum *= resc;
            m = nm;
            float expA = __expf(scA - m);  // ONE exp per (edge,head); 0 if invalid
            // ---- gather pass: 8 independent V loads in flight
            int rec_[8];
            float w_[8];
            uint_t v2_[8];
#pragma unroll
            for (int i = 0; i < 8; i++) {
                rec_[i] = __shfl(recA, i);
                int src = rec_[i] & 0x1FFFF;
                v2_[i] = *(const uint_t*)(Vb + (size_t)src * D + d0);
                w_[i] = __shfl(expA, (lane & 56) | i);    // weight, not score
            }
            // ---- consume pass
#pragma unroll
            for (int i = 0; i < 8; i++) {
                float w = w_[i];
                lsum += w;
                int r = (rec_[i] >> 17) & 7;
                int sg = ((rec_[i] >> 20) & 3) - 1;
                float v0 = bflo(v2_[i]);
                float v1 = bfhi(v2_[i]);
                float2 r2 = *(const float2*)(&l_rv[r * 132 + d0]);
                bool neu = (sg == 0);
                float f0 = neu ? sv2.x : (float)sg;
                float f1 = neu ? sv2.y : (float)sg;
                acc0 += w * v0 * r2.x * f0;
                acc1 += w * v1 * r2.y * f1;
            }
        }
        float winv = 1.f / (lsum + 1e-16f);
        float a0 = acc0 * winv, a1 = acc1 * winv;

        // gated skip + layernorm epilogue
        float alpha = 1.f / (1.f + __expf(-skip[t]));
        float p0 = alpha * a0 + (1.f - alpha) * xi.x;
        float p1 = alpha * a1 + (1.f - alpha) * xi.y;
        float rs = p0 + p1, rsq = p0 * p0 + p1 * p1;
#pragma unroll
        for (int o = 1; o < 64; o <<= 1) {
            rs += __shfl_xor(rs, o);
            rsq += __shfl_xor(rsq, o);
        }
        float mu = rs * (1.f / 128.f);
        float var = rsq * (1.f / 128.f) - mu * mu;
        float rstd = rsqrtf(var + 1e-5f);
        float2 g2 = *(const float2*)(gamma + t * D + d0);
        float2 b2 = *(const float2*)(beta + t * D + d0);
        float o0 = (p0 - mu) * rstd * g2.x + b2.x;
        float o1 = (p1 - mu) * rstd * g2.y + b2.y;
        *(float2*)(out + (size_t)dst * D + d0) = make_float2(o0, o1);
    }
}

// ---------------------------------------------------------------- launcher
extern "C" void kernel_launch(void* const* d_in, const int* in_sizes, int n_in,
                              void* d_out, int out_size, void* d_ws, size_t ws_size,
                              hipStream_t stream) {
    const float* x   = (const float*)d_in[0];
    const int*  nt   = (const int*)d_in[1];
    const int*  ei   = (const int*)d_in[2];
    const int*  et   = (const int*)d_in[3];
    const int*  es   = (const int*)d_in[4];
    const float* Wq  = (const float*)d_in[5];
    const float* bq  = (const float*)d_in[6];
    const float* Wk  = (const float*)d_in[7];
    const float* bk  = (const float*)d_in[8];
    const float* Wv  = (const float*)d_in[9];
    const float* bv  = (const float*)d_in[10];
    const float* rq  = (const float*)d_in[11];
    const float* rk  = (const float*)d_in[12];
    const float* rv  = (const float*)d_in[13];
    const float* skn = (const float*)d_in[14];
    const float* svn = (const float*)d_in[15];
    const float* rb  = (const float*)d_in[16];
    const float* skp = (const float*)d_in[17];
    const float* gma = (const float*)d_in[18];
    const float* bta = (const float*)d_in[19];
    float* out = (float*)d_out;

    int N = in_sizes[0] / D;   // 50000
    int E = in_sizes[2] / 2;   // 400000
    int NB = (N + SCAN_BS - 1) / SCAN_BS;   // scan blocks

    // workspace layout (all bf16 arrays 16B-aligned by construction)
    float*    Q     = (float*)d_ws;                    // N*D f32
    ushort_t* Kb    = (ushort_t*)(Q + (size_t)N * D);  // N*D bf16
    ushort_t* Vb    = Kb + (size_t)N * D;              // N*D bf16
    ushort_t* xs_hi = Vb + (size_t)N * D;              // N*D bf16 (sorted order)
    ushort_t* xs_lo = xs_hi + (size_t)N * D;           // N*D bf16
    ushort_t* wt_hi = xs_lo + (size_t)N * D;           // 3*4*128*128 bf16
    ushort_t* wt_lo = wt_hi + (size_t)3 * NT * D * D;
    int* deg     = (int*)(wt_lo + (size_t)3 * NT * D * D);
    int* tcnt    = deg + N;                       // 4
    int* tcur    = tcnt + NT;                     // 4
    int* row_ptr = tcur + NT;                     // N+1
    int* ecur    = row_ptr + N + 1;               // N
    int* toff    = ecur + N;                      // 5 (pad 8)
    int* sorted  = toff + 8;                      // N
    int* csr_rec = sorted + N;                    // E (packed records)
    int* bsum    = csr_rec + E;                   // NB
    int* bbase   = bsum + NB;                     // NB

    hipMemsetAsync(deg, 0, (size_t)(N + 2 * NT) * sizeof(int), stream);

    int gbNE = (max(N, E) + 255) / 256;
    k_wprep<<<(3 * NT * D * D + 255) / 256, 256, 0, stream>>>(Wq, Wk, Wv, wt_hi, wt_lo);
    k_hist<<<gbNE, 256, 0, stream>>>(nt, ei, N, E, tcnt, deg);
    k_scan1<<<NB, SCAN_BS, 0, stream>>>(deg, N, bsum);
    k_scan2<<<1, SCAN_BS, 0, stream>>>(bsum, NB, tcnt, bbase, toff, row_ptr, N, E);
    k_scan3<<<NB, SCAN_BS, 0, stream>>>(deg, N, bbase, row_ptr, ecur);
    k_scatter<<<gbNE, 256, 0, stream>>>(nt, ei, et, es, N, E, tcur, toff, sorted,
                                        ecur, csr_rec);
    k_xprep<<<(N * 32 + 255) / 256, 256, 0, stream>>>(x, sorted, N, xs_hi, xs_lo);
    int nbp = (N + 127) / 128 + NT;
    k_projm<<<dim3(nbp, 3), 512, 0, stream>>>(xs_hi, xs_lo, wt_hi, wt_lo, sorted,
                                              toff, bq, bk, bv, Q, Kb, Vb);
    k_agg<<<2048, 256, 0, stream>>>(row_ptr, csr_rec, nt, x, Q, Kb, Vb,
                                    rq, rk, rv, skn, svn, rb, skp,
                                    gma, bta, out, N);
}

// Round 12
// 303.318 us; speedup vs baseline: 3.2917x; 1.0236x over previous
//
#include <hip/hip_runtime.h>
#include <hip/hip_bf16.h>

// WeightedHGTConv: N=50000 nodes, E=400000 edges, D=128, T=4 types, R=8 rels,
// H=8 heads, DK=16.
// Pipeline: memset -> wprep -> hist -> scan x3 -> scatter -> xprep -> projm(MFMA)
//           -> fused agg
// R3: block-aggregated type counters. R4: unrolled agg gather. R6: parallel scan.
// R8: K,V stored bf16. R10: proj via split-bf16 MFMA (3 passes ~= fp32).
// R11: agg persistent blocks + exp dedup (92.5 -> ~75us).
// R12: projm was latency-bound (MfmaUtil 7%, VALUBusy 5%, occ 30%: 1185x512thr
//      = 4.6 blk/CU, uneven) -> 256thr/64-row tiles: 2370 blocks, 8 blk/CU
//      residency, 32 waves/CU. Same math order, bit-exact.

#define D 128
#define NT 4
#define NR 8
#define NH 8
#define SCAN_BS 256

typedef unsigned short ushort_t;
typedef unsigned int uint_t;
typedef __attribute__((ext_vector_type(8))) short short8v;   // 8 bf16 (4 VGPR)
typedef __attribute__((ext_vector_type(4))) float f32x4;

static __device__ __forceinline__ ushort_t f2bf(float f) {   // RNE
    uint_t u = __float_as_uint(f);
    return (ushort_t)((u + 0x7FFFu + ((u >> 16) & 1u)) >> 16);
}
static __device__ __forceinline__ float bf2f(ushort_t h) {
    return __uint_as_float(((uint_t)h) << 16);
}
static __device__ __forceinline__ float bflo(uint_t u) {     // low bf16 of packed pair
    return __uint_as_float(u << 16);
}
static __device__ __forceinline__ float bfhi(uint_t u) {     // high bf16
    return __uint_as_float(u & 0xFFFF0000u);
}

// ---------------------------------------------------------------- histogram
__global__ void k_hist(const int* __restrict__ nt, const int* __restrict__ ei,
                       int N, int E, int* __restrict__ tcnt, int* __restrict__ deg) {
    __shared__ int lcnt[NT];
    int tid = threadIdx.x;
    if (tid < NT) lcnt[tid] = 0;
    __syncthreads();
    int g = blockIdx.x * 256 + tid;
    if (g < N) atomicAdd(&lcnt[nt[g]], 1);              // LDS, cheap
    if (g < E) atomicAdd(&deg[ei[E + g]], 1);           // 50k counters, fire&forget
    __syncthreads();
    if (tid < NT && lcnt[tid]) atomicAdd(&tcnt[tid], lcnt[tid]);  // 4/block
}

// ------------------------------------------------- scan stage 1: block sums
__global__ __launch_bounds__(SCAN_BS) void k_scan1(const int* __restrict__ deg, int N,
                                                   int* __restrict__ bsum) {
    __shared__ int lds[SCAN_BS];
    int ti = threadIdx.x;
    int i = blockIdx.x * SCAN_BS + ti;
    lds[ti] = (i < N) ? deg[i] : 0;
    __syncthreads();
    for (int off = SCAN_BS >> 1; off > 0; off >>= 1) {
        if (ti < off) lds[ti] += lds[ti + off];
        __syncthreads();
    }
    if (ti == 0) bsum[blockIdx.x] = lds[0];
}

// --------------------------------- scan stage 2: scan block sums (1 block)
__global__ __launch_bounds__(SCAN_BS) void k_scan2(const int* __restrict__ bsum, int NB,
                                                   const int* __restrict__ tcnt,
                                                   int* __restrict__ bbase,
                                                   int* __restrict__ toff,
                                                   int* __restrict__ row_ptr, int N, int E) {
    __shared__ int lds[SCAN_BS];
    int ti = threadIdx.x;
    int v = (ti < NB) ? bsum[ti] : 0;
    lds[ti] = v;
    __syncthreads();
    for (int off = 1; off < SCAN_BS; off <<= 1) {
        int t = (ti >= off) ? lds[ti - off] : 0;
        __syncthreads();
        lds[ti] += t;
        __syncthreads();
    }
    if (ti < NB) bbase[ti] = lds[ti] - v;   // exclusive block base
    if (ti == 0) {
        int a = 0;
        for (int t = 0; t < NT; t++) { toff[t] = a; a += tcnt[t]; }
        toff[NT] = a;
        row_ptr[N] = E;
    }
}

// --------------------------------- scan stage 3: within-block exclusive scan
__global__ __launch_bounds__(SCAN_BS) void k_scan3(const int* __restrict__ deg, int N,
                                                   const int* __restrict__ bbase,
                                                   int* __restrict__ row_ptr,
                                                   int* __restrict__ ecur) {
    __shared__ int lds[SCAN_BS];
    int ti = threadIdx.x;
    int i = blockIdx.x * SCAN_BS + ti;
    int v = (i < N) ? deg[i] : 0;
    lds[ti] = v;
    __syncthreads();
    for (int off = 1; off < SCAN_BS; off <<= 1) {
        int t = (ti >= off) ? lds[ti - off] : 0;
        __syncthreads();
        lds[ti] += t;
        __syncthreads();
    }
    if (i < N) {
        int ex = bbase[blockIdx.x] + lds[ti] - v;
        row_ptr[i] = ex;
        ecur[i] = ex;
    }
}

// ------------------------------------------- scatter (counting sorts + edge pack)
__global__ void k_scatter(const int* __restrict__ nt, const int* __restrict__ ei,
                          const int* __restrict__ et, const int* __restrict__ es,
                          int N, int E, int* __restrict__ tcur,
                          const int* __restrict__ toff, int* __restrict__ sorted,
                          int* __restrict__ ecur, int* __restrict__ csr_rec) {
    __shared__ int lcnt[NT];
    __shared__ int lbase[NT];
    int tid = threadIdx.x;
    if (tid < NT) lcnt[tid] = 0;
    __syncthreads();
    int g = blockIdx.x * 256 + tid;
    int t = -1, myrank = 0;
    if (g < N) {
        t = nt[g];
        myrank = atomicAdd(&lcnt[t], 1);                // LDS-speed rank
    }
    __syncthreads();
    if (tid < NT) lbase[tid] = lcnt[tid] ? atomicAdd(&tcur[tid], lcnt[tid]) : 0;
    __syncthreads();
    if (t >= 0) sorted[toff[t] + lbase[t] + myrank] = g;

    if (g < E) {
        int src = ei[g];
        int d = ei[E + g];
        int r = et[g];
        int sg = es[g];
        int p = atomicAdd(&ecur[d], 1);                 // 50k counters, ~8-way
        csr_rec[p] = src | (r << 17) | ((sg + 1) << 20);
    }
}

// ------------------------------------ W prep: transpose + bf16 split (hi/lo)
__global__ void k_wprep(const float* __restrict__ Wq, const float* __restrict__ Wk,
                        const float* __restrict__ Wv,
                        ushort_t* __restrict__ wt_hi, ushort_t* __restrict__ wt_lo) {
    int g = blockIdx.x * 256 + threadIdx.x;     // over 3*4*128*128 = 196608
    if (g >= 3 * NT * D * D) return;
    int o = g & 127;
    int k = (g >> 7) & 127;
    int t = (g >> 14) & 3;
    int m = g >> 16;
    const float* Wsel = (m == 0) ? Wq : (m == 1) ? Wk : Wv;
    float w = Wsel[((size_t)t * D + k) * D + o];        // coalesced in o
    ushort_t hi = f2bf(w);
    ushort_t lo = f2bf(w - bf2f(hi));
    size_t dst = (((size_t)(m * NT + t) * D) + o) * D + k;
    wt_hi[dst] = hi;
    wt_lo[dst] = lo;
}

// ------------------------------------ x prep: gather to sorted order + split
__global__ void k_xprep(const float* __restrict__ x, const int* __restrict__ sorted,
                        int N, ushort_t* __restrict__ xs_hi, ushort_t* __restrict__ xs_lo) {
    int g = blockIdx.x * 256 + threadIdx.x;     // over N*32 float4 slots
    if (g >= N * 32) return;
    int i = g >> 5;
    int c4 = (g & 31) * 4;
    int node = sorted[i];
    float4 v = *(const float4*)(x + (size_t)node * D + c4);
    ushort4 h, l;
    h.x = f2bf(v.x); l.x = f2bf(v.x - bf2f(h.x));
    h.y = f2bf(v.y); l.y = f2bf(v.y - bf2f(h.y));
    h.z = f2bf(v.z); l.z = f2bf(v.z - bf2f(h.z));
    h.w = f2bf(v.w); l.w = f2bf(v.w - bf2f(h.w));
    *(ushort4*)(xs_hi + (size_t)i * D + c4) = h;
    *(ushort4*)(xs_lo + (size_t)i * D + c4) = l;
}

// --------------------------------------------- projections via split-bf16 MFMA
// R12: Block = 256 thr (4 waves, wave w = col group wc), 64 sorted nodes x 128
// outs, one matrix (blockIdx.y). Per wave: 4x2 C-tiles of 16x16, K-loop 4x32.
// acc += x_lo*w_hi + x_hi*w_lo + x_hi*w_hi  (lo*lo ~2^-18, dropped).
// A-frag: row=l15, k=(lane>>4)*8+j; B-frag: col=l15; C/D: col=l15,
// row=(lane>>4)*4+reg  [m89-verified layout].
__global__ __launch_bounds__(256) void k_projm(
    const ushort_t* __restrict__ xs_hi, const ushort_t* __restrict__ xs_lo,
    const ushort_t* __restrict__ wt_hi, const ushort_t* __restrict__ wt_lo,
    const int* __restrict__ sorted, const int* __restrict__ toff,
    const float* __restrict__ bq, const float* __restrict__ bk,
    const float* __restrict__ bv,
    float* __restrict__ Q, ushort_t* __restrict__ Kb, ushort_t* __restrict__ Vb) {
    __shared__ int sid[64];
    int tid = threadIdx.x;
    int b = blockIdx.x;
    // map block -> (type, 64-row slice of sorted[]) ; uniform across block
    int t = -1, p0 = 0;
    int cum = 0;
    for (int tt = 0; tt < NT; tt++) {
        int cnt_t = toff[tt + 1] - toff[tt];
        int nb = (cnt_t + 63) >> 6;
        if (t < 0 && b < cum + nb) { t = tt; p0 = toff[tt] + (b - cum) * 64; }
        cum += nb;
    }
    if (t < 0) return;
    int tend = toff[t + 1];
    if (tid < 64) sid[tid] = (p0 + tid < tend) ? sorted[p0 + tid] : -1;
    __syncthreads();

    int wc = tid >> 6, lane = tid & 63;          // wave = col group (32 cols)
    int l15 = lane & 15, kq = lane >> 4;
    int m = blockIdx.y;                          // 0:Q 1:K 2:V

    const ushort_t* wth = wt_hi + ((size_t)(m * NT + t) * D) * D;
    const ushort_t* wtl = wt_lo + ((size_t)(m * NT + t) * D) * D;

    f32x4 acc[4][2];
#pragma unroll
    for (int fa = 0; fa < 4; fa++)
#pragma unroll
        for (int fb = 0; fb < 2; fb++) acc[fa][fb] = 0.f;

#pragma unroll
    for (int k0 = 0; k0 < D; k0 += 32) {
        int kk = k0 + kq * 8;
        short8v ah[4], al[4];
#pragma unroll
        for (int fa = 0; fa < 4; fa++) {
            size_t row = (size_t)(p0 + fa * 16 + l15);
            ah[fa] = *(const short8v*)(xs_hi + row * D + kk);
            al[fa] = *(const short8v*)(xs_lo + row * D + kk);
        }
        short8v bh[2], bl[2];
#pragma unroll
        for (int fb = 0; fb < 2; fb++) {
            size_t col = (size_t)(wc * 32 + fb * 16 + l15);
            bh[fb] = *(const short8v*)(wth + col * D + kk);
            bl[fb] = *(const short8v*)(wtl + col * D + kk);
        }
#pragma unroll
        for (int fa = 0; fa < 4; fa++)
#pragma unroll
            for (int fb = 0; fb < 2; fb++) {
                acc[fa][fb] = __builtin_amdgcn_mfma_f32_16x16x32_bf16(
                    al[fa], bh[fb], acc[fa][fb], 0, 0, 0);
                acc[fa][fb] = __builtin_amdgcn_mfma_f32_16x16x32_bf16(
                    ah[fa], bl[fb], acc[fa][fb], 0, 0, 0);
                acc[fa][fb] = __builtin_amdgcn_mfma_f32_16x16x32_bf16(
                    ah[fa], bh[fb], acc[fa][fb], 0, 0, 0);
            }
    }

    const float* bm = (m == 0) ? bq : (m == 1) ? bk : bv;
    bm += t * D;
    float bias0 = bm[wc * 32 + l15];
    float bias1 = bm[wc * 32 + 16 + l15];
#pragma unroll
    for (int fa = 0; fa < 4; fa++) {
#pragma unroll
        for (int reg = 0; reg < 4; reg++) {
            int local = fa * 16 + kq * 4 + reg;
            int node = sid[local];
            if (node < 0) continue;
            float v0 = acc[fa][0][reg] + bias0;
            float v1 = acc[fa][1][reg] + bias1;
            int col0 = wc * 32 + l15;
            if (m == 0) {
                Q[(size_t)node * D + col0] = v0;
                Q[(size_t)node * D + col0 + 16] = v1;
            } else {
                ushort_t* Om = (m == 1) ? Kb : Vb;
                Om[(size_t)node * D + col0] = f2bf(v0);
                Om[(size_t)node * D + col0 + 16] = f2bf(v1);
            }
        }
    }
}

// ------------------------------- fused scores + softmax + aggregate + skip + LN
// (unchanged from R11 — persistent blocks, exp dedup, uint4 K decode)
__global__ __launch_bounds__(256) void k_agg(
    const int* __restrict__ row_ptr, const int* __restrict__ csr_rec,
    const int* __restrict__ nt, const float* __restrict__ x,
    const float* __restrict__ Qt, const ushort_t* __restrict__ Kb,
    const ushort_t* __restrict__ Vb, const float* __restrict__ rq,
    const float* __restrict__ rk, const float* __restrict__ rv,
    const float* __restrict__ skn, const float* __restrict__ svn,
    const float* __restrict__ rb, const float* __restrict__ skip,
    const float* __restrict__ gamma, const float* __restrict__ beta,
    float* __restrict__ out, int N) {
    __shared__ float l_rq[NR * 132];
    __shared__ float l_rk[NR * 132];
    __shared__ float l_rv[NR * 132];
    __shared__ float l_rb[NR * NH];
    int tid = threadIdx.x;
    for (int idx = tid; idx < NR * D; idx += 256) {
        int r = idx >> 7, c = idx & 127;
        l_rq[r * 132 + c] = rq[idx];
        l_rk[r * 132 + c] = rk[idx];
        l_rv[r * 132 + c] = rv[idx];
    }
    if (tid < NR * NH) l_rb[tid] = rb[tid];
    __syncthreads();

    int lane = tid & 63;
    int h = lane >> 3, li = lane & 7;
    int d0 = lane * 2;

    float4 sk4[4];
#pragma unroll
    for (int j = 0; j < 4; j++) sk4[j] = *(const float4*)(skn + h * 16 + 4 * j);
    float2 sv2 = *(const float2*)(svn + d0);

    int wid0 = (blockIdx.x * 256 + tid) >> 6;
    int wstride = (gridDim.x * 256) >> 6;

    for (int dst = wid0; dst < N; dst += wstride) {
        int rp0 = row_ptr[dst];
        int deg = row_ptr[dst + 1] - rp0;
        float4 q4[4];
#pragma unroll
        for (int j = 0; j < 4; j++)
            q4[j] = *(const float4*)(Qt + (size_t)dst * D + h * 16 + 4 * j);
        float2 xi = *(const float2*)(x + (size_t)dst * D + d0);
        int t = nt[dst];

        float m = -INFINITY, lsum = 0.f, acc0 = 0.f, acc1 = 0.f;

        for (int c0 = 0; c0 < deg; c0 += 8) {
            int cn = min(8, deg - c0);
            bool valid = li < cn;
            int recA = csr_rec[rp0 + c0 + (valid ? li : 0)];
            int srcA = recA & 0x1FFFF;
            int rA = (recA >> 17) & 7;
            int sgA = ((recA >> 20) & 3) - 1;
            bool neuA = (sgA == 0);
            float fsgA = (float)sgA;
            const uint4* kp4 = (const uint4*)(Kb + (size_t)srcA * D + h * 16);
            uint4 kA = kp4[0], kB = kp4[1];               // 16 bf16
            float ke[16];
            ke[0] = bflo(kA.x); ke[1] = bfhi(kA.x);
            ke[2] = bflo(kA.y); ke[3] = bfhi(kA.y);
            ke[4] = bflo(kA.z); ke[5] = bfhi(kA.z);
            ke[6] = bflo(kA.w); ke[7] = bfhi(kA.w);
            ke[8] = bflo(kB.x); ke[9] = bfhi(kB.x);
            ke[10] = bflo(kB.y); ke[11] = bfhi(kB.y);
            ke[12] = bflo(kB.z); ke[13] = bfhi(kB.z);
            ke[14] = bflo(kB.w); ke[15] = bfhi(kB.w);
            const float* rqp = &l_rq[rA * 132 + h * 16];
            const float* rkp = &l_rk[rA * 132 + h * 16];
            float dot = 0.f;
#pragma unroll
            for (int j = 0; j < 4; j++) {
                float4 a4 = *(const float4*)(rqp + 4 * j);
                float4 b4 = *(const float4*)(rkp + 4 * j);
                float f0 = neuA ? sk4[j].x : fsgA;
                float f1 = neuA ? sk4[j].y : fsgA;
                float f2 = neuA ? sk4[j].z : fsgA;
                float f3 = neuA ? sk4[j].w : fsgA;
                dot += q4[j].x * a4.x * ke[4 * j] * b4.x * f0;
                dot += q4[j].y * a4.y * ke[4 * j + 1] * b4.y * f1;
                dot += q4[j].z * a4.z * ke[4 * j + 2] * b4.z * f2;
                dot += q4[j].w * a4.w * ke[4 * j + 3] * b4.w * f3;
            }
            float scA = valid ? dot * 0.25f + l_rb[rA * NH + h] : -INFINITY;
            float cm = scA;
            cm = fmaxf(cm, __shfl_xor(cm, 1));
            cm = fmaxf(cm, __shfl_xor(cm, 2));
            cm = fmaxf(cm, __shfl_xor(cm, 4));
            float nm = fmaxf(m, cm);
            float resc = __expf(m - nm);   // 0 on first chunk
            acc0 *= resc; acc1 *= resc; lsum *= resc;
            m = nm;
            float expA = __expf(scA - m);  // ONE exp per (edge,head)
            int rec_[8];
            float w_[8];
            uint_t v2_[8];
#pragma unroll
            for (int i = 0; i < 8; i++) {
                rec_[i] = __shfl(recA, i);
                int src = rec_[i] & 0x1FFFF;
                v2_[i] = *(const uint_t*)(Vb + (size_t)src * D + d0);
                w_[i] = __shfl(expA, (lane & 56) | i);    // weight, not score
            }
#pragma unroll
            for (int i = 0; i < 8; i++) {
                float w = w_[i];
                lsum += w;
                int r = (rec_[i] >> 17) & 7;
                int sg = ((rec_[i] >> 20) & 3) - 1;
                float v0 = bflo(v2_[i]);
                float v1 = bfhi(v2_[i]);
                float2 r2 = *(const float2*)(&l_rv[r * 132 + d0]);
                bool neu = (sg == 0);
                float f0 = neu ? sv2.x : (float)sg;
                float f1 = neu ? sv2.y : (float)sg;
                acc0 += w * v0 * r2.x * f0;
                acc1 += w * v1 * r2.y * f1;
            }
        }
        float winv = 1.f / (lsum + 1e-16f);
        float a0 = acc0 * winv, a1 = acc1 * winv;

        float alpha = 1.f / (1.f + __expf(-skip[t]));
        float p0 = alpha * a0 + (1.f - alpha) * xi.x;
        float p1 = alpha * a1 + (1.f - alpha) * xi.y;
        float rs = p0 + p1, rsq = p0 * p0 + p1 * p1;
#pragma unroll
        for (int o = 1; o < 64; o <<= 1) {
            rs += __shfl_xor(rs, o);
            rsq += __shfl_xor(rsq, o);
        }
        float mu = rs * (1.f / 128.f);
        float var = rsq * (1.f / 128.f) - mu * mu;
        float rstd = rsqrtf(var + 1e-5f);
        float2 g2 = *(const float2*)(gamma + t * D + d0);
        float2 b2 = *(const float2*)(beta + t * D + d0);
        float o0 = (p0 - mu) * rstd * g2.x + b2.x;
        float o1 = (p1 - mu) * rstd * g2.y + b2.y;
        *(float2*)(out + (size_t)dst * D + d0) = make_float2(o0, o1);
    }
}

// ---------------------------------------------------------------- launcher
extern "C" void kernel_launch(void* const* d_in, const int* in_sizes, int n_in,
                              void* d_out, int out_size, void* d_ws, size_t ws_size,
                              hipStream_t stream) {
    const float* x   = (const float*)d_in[0];
    const int*  nt   = (const int*)d_in[1];
    const int*  ei   = (const int*)d_in[2];
    const int*  et   = (const int*)d_in[3];
    const int*  es   = (const int*)d_in[4];
    const float* Wq  = (const float*)d_in[5];
    const float* bq  = (const float*)d_in[6];
    const float* Wk  = (const float*)d_in[7];
    const float* bk  = (const float*)d_in[8];
    const float* Wv  = (const float*)d_in[9];
    const float* bv  = (const float*)d_in[10];
    const float* rq  = (const float*)d_in[11];
    const float* rk  = (const float*)d_in[12];
    const float* rv  = (const float*)d_in[13];
    const float* skn = (const float*)d_in[14];
    const float* svn = (const float*)d_in[15];
    const float* rb  = (const float*)d_in[16];
    const float* skp = (const float*)d_in[17];
    const float* gma = (const float*)d_in[18];
    const float* bta = (const float*)d_in[19];
    float* out = (float*)d_out;

    int N = in_sizes[0] / D;   // 50000
    int E = in_sizes[2] / 2;   // 400000
    int NB = (N + SCAN_BS - 1) / SCAN_BS;   // scan blocks

    // workspace layout (all bf16 arrays 16B-aligned by construction)
    float*    Q     = (float*)d_ws;                    // N*D f32
    ushort_t* Kb    = (ushort_t*)(Q + (size_t)N * D);  // N*D bf16
    ushort_t* Vb    = Kb + (size_t)N * D;              // N*D bf16
    ushort_t* xs_hi = Vb + (size_t)N * D;              // N*D bf16 (sorted order)
    ushort_t* xs_lo = xs_hi + (size_t)N * D;           // N*D bf16
    ushort_t* wt_hi = xs_lo + (size_t)N * D;           // 3*4*128*128 bf16
    ushort_t* wt_lo = wt_hi + (size_t)3 * NT * D * D;
    int* deg     = (int*)(wt_lo + (size_t)3 * NT * D * D);
    int* tcnt    = deg + N;                       // 4
    int* tcur    = tcnt + NT;                     // 4
    int* row_ptr = tcur + NT;                     // N+1
    int* ecur    = row_ptr + N + 1;               // N
    int* toff    = ecur + N;                      // 5 (pad 8)
    int* sorted  = toff + 8;                      // N
    int* csr_rec = sorted + N;                    // E (packed records)
    int* bsum    = csr_rec + E;                   // NB
    int* bbase   = bsum + NB;                     // NB

    hipMemsetAsync(deg, 0, (size_t)(N + 2 * NT) * sizeof(int), stream);

    int gbNE = (max(N, E) + 255) / 256;
    k_wprep<<<(3 * NT * D * D + 255) / 256, 256, 0, stream>>>(Wq, Wk, Wv, wt_hi, wt_lo);
    k_hist<<<gbNE, 256, 0, stream>>>(nt, ei, N, E, tcnt, deg);
    k_scan1<<<NB, SCAN_BS, 0, stream>>>(deg, N, bsum);
    k_scan2<<<1, SCAN_BS, 0, stream>>>(bsum, NB, tcnt, bbase, toff, row_ptr, N, E);
    k_scan3<<<NB, SCAN_BS, 0, stream>>>(deg, N, bbase, row_ptr, ecur);
    k_scatter<<<gbNE, 256, 0, stream>>>(nt, ei, et, es, N, E, tcur, toff, sorted,
                                        ecur, csr_rec);
    k_xprep<<<(N * 32 + 255) / 256, 256, 0, stream>>>(x, sorted, N, xs_hi, xs_lo);
    int nbp = (N + 63) / 64 + NT;   // 64-row tiles (R12)
    k_projm<<<dim3(nbp, 3), 256, 0, stream>>>(xs_hi, xs_lo, wt_hi, wt_lo, sorted,
                                              toff, bq, bk, bv, Q, Kb, Vb);
    k_agg<<<2048, 256, 0, stream>>>(row_ptr, csr_rec, nt, x, Q, Kb, Vb,
                                    rq, rk, rv, skn, svn, rb, skp,
                                    gma, bta, out, N);
}